// Round 14
// baseline (263.816 us; speedup 1.0000x reference)
//
#include <hip/hip_runtime.h>
#include <cstdint>
#include <cstddef>

// ---------------------------------------------------------------------------
// TransformerEncoderLayer  B=2 S=2048 D=1024 H=16 HD=64 FF=4096
// bf16 MFMA compute, fp32 accum/softmax/LN.
// R14: attn v8 -- T15 double-pipeline: QK^T(kt+1) issued alongside
//      softmax+PV(kt) (sA/sB alternating states, dist-3 staging, vmcnt(2)),
//      setprio around MFMA clusters. GEMMs frozen from R12/R13.
// ---------------------------------------------------------------------------

typedef __bf16 bf16;
typedef __bf16 bf16x2 __attribute__((ext_vector_type(2)));
typedef __bf16 bf16x4v __attribute__((ext_vector_type(4)));
typedef __bf16 bf16x8 __attribute__((ext_vector_type(8)));
typedef float  f32x4  __attribute__((ext_vector_type(4)));

#define NB 2
#define NS 2048
#define ND 1024
#define NH 16
#define NHD 64
#define NFF 4096
#define NM (NB*NS)   // 4096 rows
#define QKSCALE 0.18033688011112042f   // 0.125 * log2(e)

typedef uint32_t __attribute__((address_space(1))) gu32_t;
typedef uint32_t __attribute__((address_space(3))) lu32_t;
__device__ __forceinline__ void async_copy16(void* lds, const void* g) {
  __builtin_amdgcn_global_load_lds((gu32_t*)g, (lu32_t*)lds, 16, 0, 0);
}

__device__ __forceinline__ float gelu_f(float x) {
  return 0.5f * x * (1.0f + erff(x * 0.70710678118654752f));
}

// ---------------- prep: weight transposes + bias concat + mask + rtab + ln1 -
__global__ __launch_bounds__(256) void prep_kernel(
    const float* __restrict__ wq, const float* __restrict__ wk,
    const float* __restrict__ wv, const float* __restrict__ wo,
    const float* __restrict__ w1, const float* __restrict__ w2,
    bf16* __restrict__ wqt, bf16* __restrict__ wkt, bf16* __restrict__ wvt,
    bf16* __restrict__ wot, bf16* __restrict__ w1t, bf16* __restrict__ w2t,
    const float* __restrict__ bq, const float* __restrict__ bk,
    const float* __restrict__ bv, float* __restrict__ bcat,
    const int* __restrict__ mask, float* __restrict__ m01f,
    bf16* __restrict__ m01b, float2* __restrict__ rtab,
    const float* __restrict__ x, const float* __restrict__ ln1w,
    const float* __restrict__ ln1b, bf16* __restrict__ h1) {
  int flat = blockIdx.x;
  int t = threadIdx.x;
  if (flat < 12288) {  // ---- weight transpose + cvt ----
    __shared__ float tile[32][33];
    const float* W; bf16* Wt; long bx, by; int K, N;
    if (flat < 4096) {
      int which = flat >> 10, r = flat & 1023;
      const float* Ws[4] = {wq, wk, wv, wo};
      bf16* Wts[4] = {wqt, wkt, wvt, wot};
      W = Ws[which]; Wt = Wts[which]; bx = r & 31; by = r >> 5; K = ND; N = ND;
    } else if (flat < 8192) {
      int r = flat - 4096;
      W = w1; Wt = w1t; bx = r & 127; by = r >> 7; K = ND; N = NFF;
    } else {
      int r = flat - 8192;
      W = w2; Wt = w2t; bx = r & 31; by = r >> 5; K = NFF; N = ND;
    }
    int tx = t & 31, ty = t >> 5;
#pragma unroll
    for (int r = 0; r < 4; ++r)
      tile[ty + r*8][tx] = W[(by*32 + ty + r*8) * (long)N + bx*32 + tx];
    __syncthreads();
#pragma unroll
    for (int r = 0; r < 4; ++r)
      Wt[(bx*32 + ty + r*8) * (long)K + by*32 + tx] = (bf16)tile[tx][ty + r*8];
  } else if (flat < 12444) {  // ---- small buffers ----
    int blk = flat - 12288;
    if (blk < 12) {
      int i = blk * 256 + t;  // 3072
      bcat[i] = (i < ND) ? bq[i] : ((i < 2*ND) ? bk[i - ND] : bv[i - 2*ND]);
    } else if (blk < 28) {
      int i = (blk - 12) * 256 + t;  // 4096 = B*S
      float v = mask[i] ? 1.0f : 0.0f;
      m01f[i] = v;
      m01b[i] = (bf16)v;
    } else {
      int idx = (blk - 28) * 256 + t;  // 32768 = S*16
      int s = idx >> 4, i = idx & 15;
      float ang = (float)s * exp2f(-(float)i * (13.287712379549449f / 16.0f));
      float sn, cs;
      sincosf(ang, &sn, &cs);
      rtab[idx] = make_float2(cs, sn);
    }
  } else {  // ---- ln1 ----
    long row = flat - 12444;
    float4 v = ((const float4*)(x + row*ND))[t];
    float s  = v.x + v.y + v.z + v.w;
    float sq = v.x*v.x + v.y*v.y + v.z*v.z + v.w*v.w;
#pragma unroll
    for (int m = 1; m <= 32; m <<= 1) { s += __shfl_xor(s, m); sq += __shfl_xor(sq, m); }
    __shared__ float ss[4], ssq[4];
    if ((t & 63) == 0) { ss[t>>6] = s; ssq[t>>6] = sq; }
    __syncthreads();
    s  = ss[0] + ss[1] + ss[2] + ss[3];
    sq = ssq[0] + ssq[1] + ssq[2] + ssq[3];
    float mu = s * (1.0f/ND);
    float rs = rsqrtf(sq * (1.0f/ND) - mu*mu + 1e-5f);
    float4 wv4 = ((const float4*)ln1w)[t];
    float4 bv4 = ((const float4*)ln1b)[t];
    bf16x4v o;
    o[0] = (bf16)((v.x-mu)*rs*wv4.x + bv4.x);
    o[1] = (bf16)((v.y-mu)*rs*wv4.y + bv4.y);
    o[2] = (bf16)((v.z-mu)*rs*wv4.z + bv4.z);
    o[3] = (bf16)((v.w-mu)*rs*wv4.w + bv4.w);
    *(bf16x4v*)(h1 + row*ND + t*4) = o;
  }
}

// ---------------- V transpose: v[b,s,h,d] -> vt[b,h,d,s] -------------------
__global__ __launch_bounds__(256) void vtrans_kernel(
    const bf16* __restrict__ v, bf16* __restrict__ vt) {
  __shared__ bf16 t[64][66];
  int st = blockIdx.x, bh = blockIdx.y;   // 32 x 32
  int b = bh >> 4, h = bh & 15;
  int c = threadIdx.x & 63, rg = threadIdx.x >> 6;
  const bf16* src = v + ((long)b*NS + st*64)*ND + h*64;
#pragma unroll
  for (int i = 0; i < 16; ++i) {
    int r = rg*16 + i;
    t[r][c] = src[(long)r*ND + c];
  }
  __syncthreads();
  bf16* dst = vt + (long)bh*64*NS + st*64;
#pragma unroll
  for (int i = 0; i < 16; ++i) {
    int d = rg*16 + i;
    dst[(long)d*NS + c] = t[c][d];
  }
}

// ---------------- layernorm fp32 -> bf16 (ln2) ------------------------------
__global__ __launch_bounds__(256) void ln_kernel(
    const float* __restrict__ x, const float* __restrict__ w,
    const float* __restrict__ b, bf16* __restrict__ out) {
  long row = blockIdx.x;
  int t = threadIdx.x;
  float4 v = ((const float4*)(x + row*ND))[t];
  float s  = v.x + v.y + v.z + v.w;
  float sq = v.x*v.x + v.y*v.y + v.z*v.z + v.w*v.w;
#pragma unroll
  for (int m = 1; m <= 32; m <<= 1) { s += __shfl_xor(s, m); sq += __shfl_xor(sq, m); }
  __shared__ float ss[4], ssq[4];
  if ((t & 63) == 0) { ss[t>>6] = s; ssq[t>>6] = sq; }
  __syncthreads();
  s  = ss[0] + ss[1] + ss[2] + ss[3];
  sq = ssq[0] + ssq[1] + ssq[2] + ssq[3];
  float mu = s * (1.0f/ND);
  float rs = rsqrtf(sq * (1.0f/ND) - mu*mu + 1e-5f);
  float4 wv = ((const float4*)w)[t];
  float4 bv = ((const float4*)b)[t];
  bf16x4v o;
  o[0] = (bf16)((v.x-mu)*rs*wv.x + bv.x);
  o[1] = (bf16)((v.y-mu)*rs*wv.y + bv.y);
  o[2] = (bf16)((v.z-mu)*rs*wv.z + bv.z);
  o[3] = (bf16)((v.w-mu)*rs*wv.w + bv.w);
  *(bf16x4v*)(out + row*ND + t*4) = o;
}

// ---------------- FFN2 split-K reduce (bf16 partials): out = sum + y1 + b2 -
__global__ __launch_bounds__(256) void ffn2red_kernel(
    const bf16* __restrict__ P, const float* __restrict__ y1,
    const float* __restrict__ b2, float* __restrict__ out) {
  const long n8 = (long)NM * ND / 8;   // groups of 8 elems
  for (long i = (long)blockIdx.x*256 + threadIdx.x; i < n8;
       i += (long)gridDim.x*256) {
    bf16x8 p0 = ((const bf16x8*)P)[i];
    bf16x8 p1 = ((const bf16x8*)P)[i + n8];
    bf16x8 p2 = ((const bf16x8*)P)[i + 2*n8];
    bf16x8 p3 = ((const bf16x8*)P)[i + 3*n8];
    float4 ya = ((const float4*)y1)[2*i];
    float4 yb = ((const float4*)y1)[2*i + 1];
    int cb = (int)((i * 8) & 1023);
    float4 ba = *(const float4*)&b2[cb];
    float4 bb = *(const float4*)&b2[cb + 4];
    float4 ra, rb;
    ra.x = ((float)p0[0]+(float)p1[0])+((float)p2[0]+(float)p3[0]) + ya.x + ba.x;
    ra.y = ((float)p0[1]+(float)p1[1])+((float)p2[1]+(float)p3[1]) + ya.y + ba.y;
    ra.z = ((float)p0[2]+(float)p1[2])+((float)p2[2]+(float)p3[2]) + ya.z + ba.z;
    ra.w = ((float)p0[3]+(float)p1[3])+((float)p2[3]+(float)p3[3]) + ya.w + ba.w;
    rb.x = ((float)p0[4]+(float)p1[4])+((float)p2[4]+(float)p3[4]) + yb.x + bb.x;
    rb.y = ((float)p0[5]+(float)p1[5])+((float)p2[5]+(float)p3[5]) + yb.y + bb.y;
    rb.z = ((float)p0[6]+(float)p1[6])+((float)p2[6]+(float)p3[6]) + yb.z + bb.z;
    rb.w = ((float)p0[7]+(float)p1[7])+((float)p2[7]+(float)p3[7]) + yb.w + bb.w;
    ((float4*)out)[2*i]     = ra;
    ((float4*)out)[2*i + 1] = rb;
  }
}

// ---------------- 256^2 GEMM core (R10): BK=64, dist-2, vmcnt(8) -----------
template<int EPI>
__global__ __launch_bounds__(512, 2) void gemm256_kernel(
    const bf16* __restrict__ A, const bf16* __restrict__ Bt,
    const float* __restrict__ bias, void* __restrict__ Cout,
    const float2* __restrict__ rtab, const float* __restrict__ m01f,
    int M, int N, int K, int lda, int ldbt) {
  __shared__ __align__(16) bf16 Alds[2][256*64];   // 32KB per buffer
  __shared__ __align__(16) bf16 Blds[2][256*64];
  const int tid = threadIdx.x, lane = tid & 63, w = tid >> 6;
  const int fr = lane & 15, kg = lane >> 4;
  const int wr = w >> 2, wc = w & 3;   // 2M x 4N, wave tile 128x64
  const int kz = (EPI == 2) ? blockIdx.z : 0;
  const long kofs = (long)kz * K;      // EPI=2: slice offset in K

  const int gx = gridDim.x;
  int lin = blockIdx.y * gx + blockIdx.x;
  int nwg = gx * gridDim.y;
  int swz = (lin & 7) * (nwg >> 3) + (lin >> 3);
  const long am0 = (long)(swz / gx) * 256;
  const long bn0 = (long)(swz % gx) * 256;

  const f32x4 fzero = {0.f, 0.f, 0.f, 0.f};
  f32x4 acc[8][4];
#pragma unroll
  for (int m = 0; m < 8; ++m)
#pragma unroll
    for (int n = 0; n < 4; ++n) acc[m][n] = fzero;

  auto stage = [&](int kt, int bufi) {
#pragma unroll
    for (int i = 0; i < 4; ++i) {
      int s = i*512 + tid;
      int r = s >> 3, c = (s & 7) ^ (r & 7);
      async_copy16((char*)&Alds[bufi][0] + i*8192 + w*1024,
                   &A[(am0 + r)*(long)lda + kofs + kt + c*8]);
    }
#pragma unroll
    for (int i = 0; i < 4; ++i) {
      int s = i*512 + tid;
      int r = s >> 3, c = (s & 7) ^ (r & 7);
      async_copy16((char*)&Blds[bufi][0] + i*8192 + w*1024,
                   &Bt[(bn0 + r)*(long)ldbt + kofs + kt + c*8]);
    }
  };

  const int nk = K >> 6;   // BK = 64
  stage(0, 0);
  stage(64, 1);
  asm volatile("s_waitcnt vmcnt(8)" ::: "memory");   // tile 0 landed
  __builtin_amdgcn_s_barrier();
  __builtin_amdgcn_sched_barrier(0);

  for (int t = 0; t < nk; ++t) {
    const char* Ab = (const char*)&Alds[t & 1][0];
    const char* Bb = (const char*)&Blds[t & 1][0];
    bf16x8 bfv0[4], bfv1[4], af[4];
    // ---- phase 1: B kk0 + A m0..3 kk0 ----
#pragma unroll
    for (int n = 0; n < 4; ++n) {
      int r = wc*64 + n*16 + fr;
      bfv0[n] = *(const bf16x8*)(Bb + r*128 + ((kg ^ (r & 7)) << 4));
    }
#pragma unroll
    for (int m = 0; m < 4; ++m) {
      int r = wr*128 + m*16 + fr;
      af[m] = *(const bf16x8*)(Ab + r*128 + ((kg ^ (r & 7)) << 4));
    }
    asm volatile("s_waitcnt lgkmcnt(0)" ::: "memory");
    __builtin_amdgcn_sched_barrier(0);
    __builtin_amdgcn_s_setprio(1);
#pragma unroll
    for (int m = 0; m < 4; ++m)
#pragma unroll
      for (int n = 0; n < 4; ++n)
        acc[m][n] = __builtin_amdgcn_mfma_f32_16x16x32_bf16(af[m], bfv0[n], acc[m][n], 0, 0, 0);
    __builtin_amdgcn_s_setprio(0);
    // ---- phase 2: B kk1 + A m0..3 kk1 ----
#pragma unroll
    for (int n = 0; n < 4; ++n) {
      int r = wc*64 + n*16 + fr;
      bfv1[n] = *(const bf16x8*)(Bb + r*128 + (((4 + kg) ^ (r & 7)) << 4));
    }
#pragma unroll
    for (int m = 0; m < 4; ++m) {
      int r = wr*128 + m*16 + fr;
      af[m] = *(const bf16x8*)(Ab + r*128 + (((4 + kg) ^ (r & 7)) << 4));
    }
    asm volatile("s_waitcnt lgkmcnt(0)" ::: "memory");
    __builtin_amdgcn_sched_barrier(0);
    __builtin_amdgcn_s_setprio(1);
#pragma unroll
    for (int m = 0; m < 4; ++m)
#pragma unroll
      for (int n = 0; n < 4; ++n)
        acc[m][n] = __builtin_amdgcn_mfma_f32_16x16x32_bf16(af[m], bfv1[n], acc[m][n], 0, 0, 0);
    __builtin_amdgcn_s_setprio(0);
    // ---- phase 3: A m4..7 kk0 (bfv0 kept) ----
#pragma unroll
    for (int m = 0; m < 4; ++m) {
      int r = wr*128 + (m+4)*16 + fr;
      af[m] = *(const bf16x8*)(Ab + r*128 + ((kg ^ (r & 7)) << 4));
    }
    asm volatile("s_waitcnt lgkmcnt(0)" ::: "memory");
    __builtin_amdgcn_sched_barrier(0);
    __builtin_amdgcn_s_setprio(1);
#pragma unroll
    for (int m = 0; m < 4; ++m)
#pragma unroll
      for (int n = 0; n < 4; ++n)
        acc[m+4][n] = __builtin_amdgcn_mfma_f32_16x16x32_bf16(af[m], bfv0[n], acc[m+4][n], 0, 0, 0);
    __builtin_amdgcn_s_setprio(0);
    // ---- phase 4: A m4..7 kk1 (bfv1 kept) ----
#pragma unroll
    for (int m = 0; m < 4; ++m) {
      int r = wr*128 + (m+4)*16 + fr;
      af[m] = *(const bf16x8*)(Ab + r*128 + (((4 + kg) ^ (r & 7)) << 4));
    }
    asm volatile("s_waitcnt lgkmcnt(0)" ::: "memory");
    __builtin_amdgcn_sched_barrier(0);
    __builtin_amdgcn_s_setprio(1);
#pragma unroll
    for (int m = 0; m < 4; ++m)
#pragma unroll
      for (int n = 0; n < 4; ++n)
        acc[m+4][n] = __builtin_amdgcn_mfma_f32_16x16x32_bf16(af[m], bfv1[n], acc[m+4][n], 0, 0, 0);
    __builtin_amdgcn_s_setprio(0);

    if (t + 1 == nk) break;
    __builtin_amdgcn_s_barrier();            // all waves done reading buf t&1
    __builtin_amdgcn_sched_barrier(0);
    if (t + 2 < nk) {
      stage((t + 2) * 64, t & 1);            // refill the just-freed buffer
      asm volatile("s_waitcnt vmcnt(8)" ::: "memory");  // t+1 landed; t+2 in flight
    } else {
      asm volatile("s_waitcnt vmcnt(0)" ::: "memory");  // tail: drain t+1
    }
    __builtin_amdgcn_s_barrier();
    __builtin_amdgcn_sched_barrier(0);
  }

  const int rbase = kg * 4;
  const int region = (int)(bn0 >> 10);   // EPI=3: 0=q, 1=k, 2=v (block-uniform)
#pragma unroll
  for (int m = 0; m < 8; ++m) {
#pragma unroll
    for (int n = 0; n < 4; ++n) {
      long col = bn0 + wc*64 + n*16 + fr;
      float bia = (EPI == 2) ? 0.0f : bias[col];
#pragma unroll
      for (int j = 0; j < 4; ++j) {
        long row = am0 + wr*128 + m*16 + rbase + j;
        float val = acc[m][n][j] + bia;
        if (EPI == 1) {
          ((bf16*)Cout)[row * N + col] = (bf16)gelu_f(val);
        } else if (EPI == 2) {
          ((bf16*)Cout)[((long)kz * NM + row) * N + col] = (bf16)val;
        } else {
          long cv = col & 1023;
          if (region <= 1) {
            float pval = __shfl_xor(val, 1);     // partner dim (col^1), same row
            if (n < 2) {                         // d = n*16+fr < 32: rotate
              float2 cs = rtab[((row & (NS-1)) << 4) | ((n*16 + fr) >> 1)];
              val = (fr & 1) ? val*cs.x + pval*cs.y : val*cs.x - pval*cs.y;
            }
            if (region == 0) val *= QKSCALE;
          } else {
            val *= m01f[row];                    // premask V (masked keys -> 0)
          }
          ((bf16*)Cout)[(long)region * (NM*(long)ND) + row * ND + cv] = (bf16)val;
        }
      }
    }
  }
}

// ---------------- 128^2 GEMM, 8 waves, BK=64, depth-2 counted vmcnt --------
__global__ __launch_bounds__(512, 1) void gemm128x8_kernel(
    const bf16* __restrict__ A, const bf16* __restrict__ Bt,
    const float* __restrict__ bias, const float* __restrict__ res,
    float* __restrict__ Cout, int M, int N, int K) {
  __shared__ __align__(16) bf16 Alds[4][128*64];   // 16KB per buffer
  __shared__ __align__(16) bf16 Blds[4][128*64];
  const int tid = threadIdx.x, lane = tid & 63, w = tid >> 6;
  const int fr = lane & 15, kg = lane >> 4;
  const int wr = w >> 1, wc = w & 1;   // 4M x 2N

  const int gx = gridDim.x;
  int lin = blockIdx.y * gx + blockIdx.x;
  int nwg = gx * gridDim.y;
  int swz = (lin & 7) * (nwg >> 3) + (lin >> 3);
  const long am0 = (long)(swz / gx) * 128;
  const long bn0 = (long)(swz % gx) * 128;

  const f32x4 fzero = {0.f, 0.f, 0.f, 0.f};
  f32x4 acc[2][4];
#pragma unroll
  for (int m = 0; m < 2; ++m)
#pragma unroll
    for (int n = 0; n < 4; ++n) acc[m][n] = fzero;

  auto stage = [&](int kt, int bufi) {
#pragma unroll
    for (int i = 0; i < 2; ++i) {
      int s = i*512 + tid;
      int r = s >> 3, c = (s & 7) ^ (r & 7);
      async_copy16((char*)&Alds[bufi][0] + i*8192 + w*1024,
                   &A[(am0 + r)*K + kt + c*8]);
      async_copy16((char*)&Blds[bufi][0] + i*8192 + w*1024,
                   &Bt[(bn0 + r)*K + kt + c*8]);
    }
  };

  const int nk = K >> 6;
  stage(0, 0);
  stage(64, 1);
  asm volatile("s_waitcnt vmcnt(4)" ::: "memory");
  __builtin_amdgcn_s_barrier();
  __builtin_amdgcn_sched_barrier(0);

  for (int t = 0; t < nk; ++t) {
    const int cur = t & 3;
    if (t + 2 < nk) stage((t + 2) * 64, (t + 2) & 3);
    const char* Ab = (const char*)&Alds[cur][0];
    const char* Bb = (const char*)&Blds[cur][0];
    bf16x8 af[2][2], bfv[2][4];
#pragma unroll
    for (int kk = 0; kk < 2; ++kk) {
#pragma unroll
      for (int m = 0; m < 2; ++m) {
        int r = wr*32 + m*16 + fr;
        af[kk][m] = *(const bf16x8*)(Ab + r*128 + (((kk*4 + kg) ^ (r & 7)) << 4));
      }
#pragma unroll
      for (int n = 0; n < 4; ++n) {
        int r = wc*64 + n*16 + fr;
        bfv[kk][n] = *(const bf16x8*)(Bb + r*128 + (((kk*4 + kg) ^ (r & 7)) << 4));
      }
    }
    asm volatile("s_waitcnt lgkmcnt(0)" ::: "memory");
    __builtin_amdgcn_sched_barrier(0);
    __builtin_amdgcn_s_setprio(1);
#pragma unroll
    for (int kk = 0; kk < 2; ++kk)
#pragma unroll
      for (int m = 0; m < 2; ++m)
#pragma unroll
        for (int n = 0; n < 4; ++n)
          acc[m][n] = __builtin_amdgcn_mfma_f32_16x16x32_bf16(af[kk][m], bfv[kk][n], acc[m][n], 0, 0, 0);
    __builtin_amdgcn_s_setprio(0);
    if (t + 2 < nk) { asm volatile("s_waitcnt vmcnt(4)" ::: "memory"); }
    else            { asm volatile("s_waitcnt vmcnt(0)" ::: "memory"); }
    __builtin_amdgcn_s_barrier();
    __builtin_amdgcn_sched_barrier(0);
  }

  const int rbase = kg * 4;
#pragma unroll
  for (int m = 0; m < 2; ++m) {
#pragma unroll
    for (int n = 0; n < 4; ++n) {
      long col = bn0 + wc*64 + n*16 + fr;
      float bia = bias[col];
#pragma unroll
      for (int j = 0; j < 4; ++j) {
        long row = am0 + wr*32 + m*16 + rbase + j;
        Cout[row * N + col] = acc[m][n][j] + bia + res[row * N + col];
      }
    }
  }
}

// ---------------- flash attention v8: T15 double-pipeline ------------------
// While softmax+PV of tile kt runs, QK^T MFMAs of tile kt+1 are in the same
// window (independent: read K[(kt+1)&3], write the other sacc state).
// Staging at distance 3 (4 buffers = {V:kt, K:kt+1, idle:kt+2, write:kt+3}).
//   WAR: buf (kt+3)&3 held tile kt-1; V[kt-1] read during iter kt-1 and its
//        ds_reads complete before iter kt-1's end barrier -> 1 barrier ahead
//        of the stage in iter kt. K[kt-1] read in iter kt-2 (2 barriers).
//   RAW: end-of-iter-kt vmcnt(2) leaves only tile (kt+3)'s 2 loads in
//        flight -> tiles <= kt+2 landed; iter kt+1 reads K[kt+2], V[kt+1].
//   Tail (kt >= NT-3): no stage; vmcnt(0) drains the last staged pair.
__global__ __launch_bounds__(512, 4) void attn_kernel(
    const bf16* __restrict__ q, const bf16* __restrict__ k,
    const bf16* __restrict__ vt, const bf16* __restrict__ m01b,
    bf16* __restrict__ out) {
  int lin = blockIdx.y * 16 + blockIdx.x;       // grid (16, 32) = 512 blocks
  int swz = (lin & 7) * 64 + (lin >> 3);
  const int qt = swz & 15;                      // 16 q-tiles of 128 rows
  const int bh = swz >> 4;                      // 0..31
  const int b = bh >> 4, h = bh & 15;
  const int tid = threadIdx.x, lane = tid & 63, w = tid >> 6;
  const int fr = lane & 15, kg = lane >> 4;
  const int k8 = kg * 8;
  const int frl = fr & 3, frh = fr >> 2;

  // K of buf i at byte (i*16384), V of buf i at (i*16384 + 8192). 64KB total.
  __shared__ __align__(16) bf16 KVlds[4][2][64*64];
  __shared__ __align__(16) bf16 Mlds[NS];         // mask01 row (4KB)

  const long qrow = (long)qt*128 + w*16 + fr;
  const bf16* qbase = q + ((long)b*NS + qrow)*ND + h*NHD;
  bf16x8 qf[2];
  qf[0] = *(const bf16x8*)(qbase + k8);
  qf[1] = *(const bf16x8*)(qbase + 32 + k8);

  const bf16* kbase = k + (long)b*NS*ND + h*NHD;
  const bf16* vtb = vt + (long)bh*64*NS;
  const bf16* mbase = m01b + (long)b*NS;

  if (w < 4) async_copy16((char*)Mlds + w*1024, mbase + tid*8);

  // ---- pinned per-lane LDS byte offsets (opaque to remat) ----
  int aK[4][2], aV[2][4];
#pragma unroll
  for (int n = 0; n < 4; ++n) {
    int r = (frh << 3) + ((n & 1) << 2) + frl + ((n >> 1) << 5);
    int swzr = (r & 7) ^ (((r >> 3) & 1) << 2);
#pragma unroll
    for (int kk = 0; kk < 2; ++kk) {
      aK[n][kk] = r*128 + ((((kk << 2) | kg) ^ swzr) << 4);
      asm("" : "+v"(aK[n][kk]));
    }
  }
#pragma unroll
  for (int kk = 0; kk < 2; ++kk)
#pragma unroll
    for (int n2 = 0; n2 < 4; ++n2) {
      int r = n2*16 + fr;
      aV[kk][n2] = r*128 + ((((kk << 2) | kg) ^ (r & 7)) << 4);
      asm("" : "+v"(aV[kk][n2]));
    }

  // ---- staging pointers (advance per staged tile) ----
  const int srow = tid >> 3, sc = tid & 7;
  const int csK = (sc ^ (srow & 7) ^ (((srow >> 3) & 1) << 2));
  const int csV = (sc ^ (srow & 7));
  const bf16* kp = kbase + (long)srow*ND + csK*8;
  const bf16* vp = vtb + (long)srow*NS + csV*8;
  const int ldsoff = w*1024;

  const f32x4 fzero = {0.f, 0.f, 0.f, 0.f};
  f32x4 oacc[4], oaccL = fzero;
#pragma unroll
  for (int n = 0; n < 4; ++n) oacc[n] = fzero;

  // prologue: stage tiles 0,1,2 into bufs 0,1,2
#pragma unroll
  for (int tpre = 0; tpre < 3; ++tpre) {
    async_copy16((char*)KVlds + tpre*16384 + ldsoff, kp);
    async_copy16((char*)KVlds + tpre*16384 + 8192 + ldsoff, vp);
    kp += 64*ND; vp += 64;
  }
  asm volatile("s_waitcnt vmcnt(2)" ::: "memory");   // tiles 0,1 (and mask) in
  __builtin_amdgcn_s_barrier();
  __builtin_amdgcn_sched_barrier(0);

  const int NT = NS / 64;   // 32

  // prologue compute: sA = QK^T(tile 0) from buf0
  f32x4 sA[4], sB[4];
#pragma unroll
  for (int n = 0; n < 4; ++n) sA[n] = fzero;
  __builtin_amdgcn_s_setprio(1);
#pragma unroll
  for (int n = 0; n < 4; ++n)
#pragma unroll
    for (int kk = 0; kk < 2; ++kk) {
      bf16x8 kf = *(const bf16x8*)((const char*)KVlds + 0*16384 + aK[n][kk]);
      sA[n] = __builtin_amdgcn_mfma_f32_16x16x32_bf16(kf, qf[kk], sA[n], 0, 0, 0);
    }
  __builtin_amdgcn_s_setprio(0);

#define ATTN_TILE(KT, BUF, SIN, SOUT)                                          \
  {                                                                            \
    const int kt_ = (KT);                                                      \
    if (kt_ + 3 < NT) {                                                        \
      async_copy16((char*)KVlds + (((BUF)+3)&3)*16384 + ldsoff, kp);           \
      async_copy16((char*)KVlds + (((BUF)+3)&3)*16384 + 8192 + ldsoff, vp);    \
      kp += 64*ND; vp += 64;                                                   \
    }                                                                          \
    /* QK^T for tile kt_+1 (independent of softmax/PV below) */                \
    if (kt_ + 1 < NT) {                                                        \
      _Pragma("unroll")                                                        \
      for (int n = 0; n < 4; ++n) SOUT[n] = fzero;                             \
      __builtin_amdgcn_s_setprio(1);                                           \
      _Pragma("unroll")                                                        \
      for (int n = 0; n < 4; ++n) {                                            \
        _Pragma("unroll")                                                      \
        for (int kk = 0; kk < 2; ++kk) {                                       \
          bf16x8 kf = *(const bf16x8*)((const char*)KVlds +                    \
                                       (((BUF)+1)&3)*16384 + aK[n][kk]);       \
          SOUT[n] = __builtin_amdgcn_mfma_f32_16x16x32_bf16(kf, qf[kk],        \
                                                            SOUT[n], 0, 0, 0); \
        }                                                                      \
      }                                                                        \
      __builtin_amdgcn_s_setprio(0);                                           \
    }                                                                          \
    /* softmax + l-sum + PV for tile kt_ from SIN */                           \
    bf16x8 vbm0 = *(const bf16x8*)&Mlds[kt_*64 + k8];                          \
    bf16x8 vbm1 = *(const bf16x8*)&Mlds[kt_*64 + 32 + k8];                     \
    float p[4][4];                                                             \
    _Pragma("unroll")                                                          \
    for (int n = 0; n < 4; ++n) {                                              \
      p[n][0] = exp2f(SIN[n][0]);                                              \
      p[n][1] = exp2f(SIN[n][1]);                                              \
      p[n][2] = exp2f(SIN[n][2]);                                              \
      p[n][3] = exp2f(SIN[n][3]);                                              \
    }                                                                          \
    bf16x8 paf[2];                                                             \
    _Pragma("unroll")                                                          \
    for (int n = 0; n < 4; ++n) {                                              \
      _Pragma("unroll")                                                        \
      for (int j = 0; j < 4; ++j)                                              \
        paf[n >> 1][((n & 1) << 2) + j] = (bf16)p[n][j];                       \
    }                                                                          \
    oaccL = __builtin_amdgcn_mfma_f32_16x16x32_bf16(paf[0], vbm0, oaccL,       \
                                                    0, 0, 0);                  \
    oaccL = __builtin_amdgcn_mfma_f32_16x16x32_bf16(paf[1], vbm1, oaccL,       \
                                                    0, 0, 0);                  \
    __builtin_amdgcn_s_setprio(1);                                             \
    _Pragma("unroll")                                                          \
    for (int kk = 0; kk < 2; ++kk) {                                           \
      _Pragma("unroll")                                                        \
      for (int n2 = 0; n2 < 4; ++n2) {                                         \
        bf16x8 vb8 = *(const bf16x8*)((const char*)KVlds + (BUF)*16384 +       \
                                      8192 + aV[kk][n2]);                      \
        oacc[n2] = __builtin_amdgcn_mfma_f32_16x16x32_bf16(paf[kk], vb8,       \
                                                           oacc[n2], 0, 0, 0); \
      }                                                                        \
    }                                                                          \
    __builtin_amdgcn_s_setprio(0);                                             \
    if (kt_ + 3 < NT) { asm volatile("s_waitcnt vmcnt(2)" ::: "memory"); }     \
    else              { asm volatile("s_waitcnt vmcnt(0)" ::: "memory"); }     \
    __builtin_amdgcn_s_barrier();                                              \
    __builtin_amdgcn_sched_barrier(0);                                         \
  }

  for (int it = 0; it < NT/4; ++it) {
    int kt0 = it * 4;
    ATTN_TILE(kt0 + 0, 0, sA, sB)
    ATTN_TILE(kt0 + 1, 1, sB, sA)
    ATTN_TILE(kt0 + 2, 2, sA, sB)
    ATTN_TILE(kt0 + 3, 3, sB, sA)
  }
#undef ATTN_TILE

  // epilogue: O / l  (oaccL[j] is the row-sum for row kg*4+j, all lanes agree)
#pragma unroll
  for (int j = 0; j < 4; ++j) {
    float inv = 1.0f / oaccL[j];
    long orow = (long)qt*128 + w*16 + kg*4 + j;
    bf16* ob = out + ((long)b*NS + orow)*ND + h*NHD;
#pragma unroll
    for (int n2 = 0; n2 < 4; ++n2) ob[n2*16 + fr] = (bf16)(oacc[n2][j] * inv);
  }
}

// ---------------------------------------------------------------------------
extern "C" void kernel_launch(void* const* d_in, const int* in_sizes, int n_in,
                              void* d_out, int out_size, void* d_ws, size_t ws_size,
                              hipStream_t stream) {
  const float* x    = (const float*)d_in[0];
  const int*   mask = (const int*)d_in[1];
  const float* wq   = (const float*)d_in[2];
  const float* bq   = (const float*)d_in[3];
  const float* wk   = (const float*)d_in[4];
  const float* bk   = (const float*)d_in[5];
  const float* wv   = (const float*)d_in[6];
  const float* bv   = (const float*)d_in[7];
  const float* wo   = (const float*)d_in[8];
  const float* bo   = (const float*)d_in[9];
  const float* ln1w = (const float*)d_in[10];
  const float* ln1b = (const float*)d_in[11];
  const float* ln2w = (const float*)d_in[12];
  const float* ln2b = (const float*)d_in[13];
  const float* w1   = (const float*)d_in[14];
  const float* b1   = (const float*)d_in[15];
  const float* w2   = (const float*)d_in[16];
  const float* b2   = (const float*)d_in[17];
  float* out = (float*)d_out;

  char* ws = (char*)d_ws;
  const size_t MB = 1024ull * 1024ull;
  bf16* wqt = (bf16*)(ws + 0*MB);    // wq|wk|wv contiguous for fused QKV
  bf16* wkt = (bf16*)(ws + 2*MB);
  bf16* wvt = (bf16*)(ws + 4*MB);
  bf16* wot = (bf16*)(ws + 6*MB);
  bf16* w1t = (bf16*)(ws + 8*MB);    // 8MB
  bf16* w2t = (bf16*)(ws + 16*MB);   // 8MB
  bf16* h1   = (bf16*)(ws + 24*MB);  // ln1 out (dead after QKV)
  bf16* qb   = (bf16*)(ws + 32*MB);  // q | k | v contiguous (8MB each)
  bf16* kb   = (bf16*)(ws + 40*MB);
  bf16* vb   = (bf16*)(ws + 48*MB);  // v row-major (dead after vtrans)
  bf16* vtb  = h1;                   // vt[b][h][d][s] reuses h1 slot
  bf16* attnb = (bf16*)(ws + 72*MB); // attn out (consumed before ln2 -> h2)
  bf16* f1   = (bf16*)(ws + 24*MB);  // FFN1 out 32MB, alias vt/q/k/v (dead)
  float* y1  = (float*)(ws + 56*MB); // 16MB
  bf16* h2   = (bf16*)(ws + 72*MB);  // 8MB (after attnb consumed)
  float* bcat = (float*)(ws + 80*MB);            // 12KB
  float* m01f = (float*)(ws + 80*MB + 16*1024);  // 16KB (B*S f32)
  bf16*  m01b = (bf16*) (ws + 80*MB + 32*1024);  // 8KB  (B*S bf16)
  float2* rtab = (float2*)(ws + 80*MB + 48*1024);// 256KB (S*16 float2)
  bf16* pK   = (bf16*)(ws + 84*MB);              // 32MB: 4 x [NM][ND] bf16
  const bool use_splitk = (ws_size >= 116ull*MB);
  (void)in_sizes; (void)n_in; (void)out_size;

  // prep: all weight transposes + bias concat + mask01 + rope table + ln1
  prep_kernel<<<16540, 256, 0, stream>>>(wq, wk, wv, wo, w1, w2,
                                         wqt, wkt, wvt, wot, w1t, w2t,
                                         bq, bk, bv, bcat, mask, m01f, m01b,
                                         rtab, x, ln1w, ln1b, h1);

  // fused QKV (256^2 core) + RoPE(q,k) + scale(q) + premask(v, row-major)
  gemm256_kernel<3><<<dim3(12, 16), 512, 0, stream>>>(h1, wqt, bcat, qb,
                                                      rtab, m01f, NM, 3*ND, ND,
                                                      ND, ND);
  // v[b,s,h,d] -> vt[b,h,d,s]  (h1 slot; h1 is dead now)
  vtrans_kernel<<<dim3(32, 32), 256, 0, stream>>>(vb, vtb);

  attn_kernel<<<dim3(16, 32), 512, 0, stream>>>(qb, kb, vtb, m01b, attnb);

  // out-proj + residual(x) -> y1 (fp32)
  gemm128x8_kernel<<<dim3(8, 32), 512, 0, stream>>>(attnb, wot, bo, x, y1,
                                                    NM, ND, ND);
  ln_kernel<<<NM, 256, 0, stream>>>(y1, ln2w, ln2b, h2);
  // FFN1 + GELU (256^2 core) -> f1 (bf16)
  gemm256_kernel<1><<<dim3(16, 16), 512, 0, stream>>>(h2, w1t, b1, f1,
                                                      nullptr, nullptr,
                                                      NM, NFF, ND, ND, ND);
  if (use_splitk) {
    // FFN2 split-K4 (256^2 core per slice) -> bf16 partials + fused reduce
    gemm256_kernel<2><<<dim3(4, 16, 4), 512, 0, stream>>>(f1, w2t, nullptr, pK,
                                                          nullptr, nullptr,
                                                          NM, ND, ND, NFF, NFF);
    ffn2red_kernel<<<2048, 256, 0, stream>>>(pK, y1, b2, out);
  } else {
    // fallback: R8 path
    gemm128x8_kernel<<<dim3(8, 32), 512, 0, stream>>>(f1, w2t, b2, y1, out,
                                                      NM, ND, NFF);
  }
}

// Round 15
// 262.588 us; speedup vs baseline: 1.0047x; 1.0047x over previous
//
#include <hip/hip_runtime.h>
#include <cstdint>
#include <cstddef>

// ---------------------------------------------------------------------------
// TransformerEncoderLayer  B=2 S=2048 D=1024 H=16 HD=64 FF=4096
// bf16 MFMA compute, fp32 accum/softmax/LN.
// R15: revert T15 (null) -> attn v7 + fzero-as-C trick (no per-tile sacc
//      clear); prep transposes use 64-row tiles + bf16x2 writes (full cache
//      lines). GEMMs frozen (R10 core), FFN2 split-K + bf16 reduce kept.
// ---------------------------------------------------------------------------

typedef __bf16 bf16;
typedef __bf16 bf16x2 __attribute__((ext_vector_type(2)));
typedef __bf16 bf16x4v __attribute__((ext_vector_type(4)));
typedef __bf16 bf16x8 __attribute__((ext_vector_type(8)));
typedef float  f32x4  __attribute__((ext_vector_type(4)));

#define NB 2
#define NS 2048
#define ND 1024
#define NH 16
#define NHD 64
#define NFF 4096
#define NM (NB*NS)   // 4096 rows
#define QKSCALE 0.18033688011112042f   // 0.125 * log2(e)

typedef uint32_t __attribute__((address_space(1))) gu32_t;
typedef uint32_t __attribute__((address_space(3))) lu32_t;
__device__ __forceinline__ void async_copy16(void* lds, const void* g) {
  __builtin_amdgcn_global_load_lds((gu32_t*)g, (lu32_t*)lds, 16, 0, 0);
}

__device__ __forceinline__ float gelu_f(float x) {
  return 0.5f * x * (1.0f + erff(x * 0.70710678118654752f));
}

// ---------------- prep: weight transposes + bias concat + mask + rtab + ln1 -
// Transpose tiling: 64 input rows x 32 input cols per block; output writes
// are bf16x2 (64 contiguous bf16 = 128B per wave-row -> full cache lines).
// blocks: [0,2048) wq/wk/wv/wo (512 each), [2048,4096) w1, [4096,6144) w2,
// [6144,6300) small buffers, [6300,10396) ln1 rows.
__global__ __launch_bounds__(256) void prep_kernel(
    const float* __restrict__ wq, const float* __restrict__ wk,
    const float* __restrict__ wv, const float* __restrict__ wo,
    const float* __restrict__ w1, const float* __restrict__ w2,
    bf16* __restrict__ wqt, bf16* __restrict__ wkt, bf16* __restrict__ wvt,
    bf16* __restrict__ wot, bf16* __restrict__ w1t, bf16* __restrict__ w2t,
    const float* __restrict__ bq, const float* __restrict__ bk,
    const float* __restrict__ bv, float* __restrict__ bcat,
    const int* __restrict__ mask, float* __restrict__ m01f,
    bf16* __restrict__ m01b, float2* __restrict__ rtab,
    const float* __restrict__ x, const float* __restrict__ ln1w,
    const float* __restrict__ ln1b, bf16* __restrict__ h1) {
  int flat = blockIdx.x;
  int t = threadIdx.x;
  if (flat < 6144) {  // ---- weight transpose + cvt (64x32 in-tile) ----
    __shared__ float tile[64][33];
    const float* W; bf16* Wt; long bx, by; int K, N;
    if (flat < 2048) {
      int which = flat >> 9, r = flat & 511;
      const float* Ws[4] = {wq, wk, wv, wo};
      bf16* Wts[4] = {wqt, wkt, wvt, wot};
      W = Ws[which]; Wt = Wts[which]; bx = r & 31; by = r >> 5; K = ND; N = ND;
    } else if (flat < 4096) {
      int r = flat - 2048;
      W = w1; Wt = w1t; bx = r & 127; by = r >> 7; K = ND; N = NFF;
    } else {
      int r = flat - 4096;
      W = w2; Wt = w2t; bx = r & 31; by = r >> 5; K = NFF; N = ND;
    }
    int tx = t & 31, ty = t >> 5;
#pragma unroll
    for (int rr = 0; rr < 8; ++rr)
      tile[rr*8 + ty][tx] = W[(by*64 + rr*8 + ty) * (long)N + bx*32 + tx];
    __syncthreads();
#pragma unroll
    for (int rr = 0; rr < 4; ++rr) {
      int ory = ty*4 + rr;              // output row within tile (input col)
      bf16x2 v2;
      v2[0] = (bf16)tile[2*tx][ory];
      v2[1] = (bf16)tile[2*tx + 1][ory];
      *(bf16x2*)&Wt[(bx*32 + ory) * (long)K + by*64 + 2*tx] = v2;
    }
  } else if (flat < 6300) {  // ---- small buffers ----
    int blk = flat - 6144;
    if (blk < 12) {
      int i = blk * 256 + t;  // 3072
      bcat[i] = (i < ND) ? bq[i] : ((i < 2*ND) ? bk[i - ND] : bv[i - 2*ND]);
    } else if (blk < 28) {
      int i = (blk - 12) * 256 + t;  // 4096 = B*S
      float v = mask[i] ? 1.0f : 0.0f;
      m01f[i] = v;
      m01b[i] = (bf16)v;
    } else {
      int idx = (blk - 28) * 256 + t;  // 32768 = S*16
      int s = idx >> 4, i = idx & 15;
      float ang = (float)s * exp2f(-(float)i * (13.287712379549449f / 16.0f));
      float sn, cs;
      sincosf(ang, &sn, &cs);
      rtab[idx] = make_float2(cs, sn);
    }
  } else {  // ---- ln1 ----
    long row = flat - 6300;
    float4 v = ((const float4*)(x + row*ND))[t];
    float s  = v.x + v.y + v.z + v.w;
    float sq = v.x*v.x + v.y*v.y + v.z*v.z + v.w*v.w;
#pragma unroll
    for (int m = 1; m <= 32; m <<= 1) { s += __shfl_xor(s, m); sq += __shfl_xor(sq, m); }
    __shared__ float ss[4], ssq[4];
    if ((t & 63) == 0) { ss[t>>6] = s; ssq[t>>6] = sq; }
    __syncthreads();
    s  = ss[0] + ss[1] + ss[2] + ss[3];
    sq = ssq[0] + ssq[1] + ssq[2] + ssq[3];
    float mu = s * (1.0f/ND);
    float rs = rsqrtf(sq * (1.0f/ND) - mu*mu + 1e-5f);
    float4 wv4 = ((const float4*)ln1w)[t];
    float4 bv4 = ((const float4*)ln1b)[t];
    bf16x4v o;
    o[0] = (bf16)((v.x-mu)*rs*wv4.x + bv4.x);
    o[1] = (bf16)((v.y-mu)*rs*wv4.y + bv4.y);
    o[2] = (bf16)((v.z-mu)*rs*wv4.z + bv4.z);
    o[3] = (bf16)((v.w-mu)*rs*wv4.w + bv4.w);
    *(bf16x4v*)(h1 + row*ND + t*4) = o;
  }
}

// ---------------- V transpose: v[b,s,h,d] -> vt[b,h,d,s] -------------------
__global__ __launch_bounds__(256) void vtrans_kernel(
    const bf16* __restrict__ v, bf16* __restrict__ vt) {
  __shared__ bf16 t[64][66];
  int st = blockIdx.x, bh = blockIdx.y;   // 32 x 32
  int b = bh >> 4, h = bh & 15;
  int c = threadIdx.x & 63, rg = threadIdx.x >> 6;
  const bf16* src = v + ((long)b*NS + st*64)*ND + h*64;
#pragma unroll
  for (int i = 0; i < 16; ++i) {
    int r = rg*16 + i;
    t[r][c] = src[(long)r*ND + c];
  }
  __syncthreads();
  bf16* dst = vt + (long)bh*64*NS + st*64;
#pragma unroll
  for (int i = 0; i < 16; ++i) {
    int d = rg*16 + i;
    dst[(long)d*NS + c] = t[c][d];
  }
}

// ---------------- layernorm fp32 -> bf16 (ln2) ------------------------------
__global__ __launch_bounds__(256) void ln_kernel(
    const float* __restrict__ x, const float* __restrict__ w,
    const float* __restrict__ b, bf16* __restrict__ out) {
  long row = blockIdx.x;
  int t = threadIdx.x;
  float4 v = ((const float4*)(x + row*ND))[t];
  float s  = v.x + v.y + v.z + v.w;
  float sq = v.x*v.x + v.y*v.y + v.z*v.z + v.w*v.w;
#pragma unroll
  for (int m = 1; m <= 32; m <<= 1) { s += __shfl_xor(s, m); sq += __shfl_xor(sq, m); }
  __shared__ float ss[4], ssq[4];
  if ((t & 63) == 0) { ss[t>>6] = s; ssq[t>>6] = sq; }
  __syncthreads();
  s  = ss[0] + ss[1] + ss[2] + ss[3];
  sq = ssq[0] + ssq[1] + ssq[2] + ssq[3];
  float mu = s * (1.0f/ND);
  float rs = rsqrtf(sq * (1.0f/ND) - mu*mu + 1e-5f);
  float4 wv = ((const float4*)w)[t];
  float4 bv = ((const float4*)b)[t];
  bf16x4v o;
  o[0] = (bf16)((v.x-mu)*rs*wv.x + bv.x);
  o[1] = (bf16)((v.y-mu)*rs*wv.y + bv.y);
  o[2] = (bf16)((v.z-mu)*rs*wv.z + bv.z);
  o[3] = (bf16)((v.w-mu)*rs*wv.w + bv.w);
  *(bf16x4v*)(out + row*ND + t*4) = o;
}

// ---------------- FFN2 split-K reduce (bf16 partials): out = sum + y1 + b2 -
__global__ __launch_bounds__(256) void ffn2red_kernel(
    const bf16* __restrict__ P, const float* __restrict__ y1,
    const float* __restrict__ b2, float* __restrict__ out) {
  const long n8 = (long)NM * ND / 8;   // groups of 8 elems
  for (long i = (long)blockIdx.x*256 + threadIdx.x; i < n8;
       i += (long)gridDim.x*256) {
    bf16x8 p0 = ((const bf16x8*)P)[i];
    bf16x8 p1 = ((const bf16x8*)P)[i + n8];
    bf16x8 p2 = ((const bf16x8*)P)[i + 2*n8];
    bf16x8 p3 = ((const bf16x8*)P)[i + 3*n8];
    float4 ya = ((const float4*)y1)[2*i];
    float4 yb = ((const float4*)y1)[2*i + 1];
    int cb = (int)((i * 8) & 1023);
    float4 ba = *(const float4*)&b2[cb];
    float4 bb = *(const float4*)&b2[cb + 4];
    float4 ra, rb;
    ra.x = ((float)p0[0]+(float)p1[0])+((float)p2[0]+(float)p3[0]) + ya.x + ba.x;
    ra.y = ((float)p0[1]+(float)p1[1])+((float)p2[1]+(float)p3[1]) + ya.y + ba.y;
    ra.z = ((float)p0[2]+(float)p1[2])+((float)p2[2]+(float)p3[2]) + ya.z + ba.z;
    ra.w = ((float)p0[3]+(float)p1[3])+((float)p2[3]+(float)p3[3]) + ya.w + ba.w;
    rb.x = ((float)p0[4]+(float)p1[4])+((float)p2[4]+(float)p3[4]) + yb.x + bb.x;
    rb.y = ((float)p0[5]+(float)p1[5])+((float)p2[5]+(float)p3[5]) + yb.y + bb.y;
    rb.z = ((float)p0[6]+(float)p1[6])+((float)p2[6]+(float)p3[6]) + yb.z + bb.z;
    rb.w = ((float)p0[7]+(float)p1[7])+((float)p2[7]+(float)p3[7]) + yb.w + bb.w;
    ((float4*)out)[2*i]     = ra;
    ((float4*)out)[2*i + 1] = rb;
  }
}

// ---------------- 256^2 GEMM core (R10): BK=64, dist-2, vmcnt(8) -----------
template<int EPI>
__global__ __launch_bounds__(512, 2) void gemm256_kernel(
    const bf16* __restrict__ A, const bf16* __restrict__ Bt,
    const float* __restrict__ bias, void* __restrict__ Cout,
    const float2* __restrict__ rtab, const float* __restrict__ m01f,
    int M, int N, int K, int lda, int ldbt) {
  __shared__ __align__(16) bf16 Alds[2][256*64];   // 32KB per buffer
  __shared__ __align__(16) bf16 Blds[2][256*64];
  const int tid = threadIdx.x, lane = tid & 63, w = tid >> 6;
  const int fr = lane & 15, kg = lane >> 4;
  const int wr = w >> 2, wc = w & 3;   // 2M x 4N, wave tile 128x64
  const int kz = (EPI == 2) ? blockIdx.z : 0;
  const long kofs = (long)kz * K;      // EPI=2: slice offset in K

  const int gx = gridDim.x;
  int lin = blockIdx.y * gx + blockIdx.x;
  int nwg = gx * gridDim.y;
  int swz = (lin & 7) * (nwg >> 3) + (lin >> 3);
  const long am0 = (long)(swz / gx) * 256;
  const long bn0 = (long)(swz % gx) * 256;

  const f32x4 fzero = {0.f, 0.f, 0.f, 0.f};
  f32x4 acc[8][4];
#pragma unroll
  for (int m = 0; m < 8; ++m)
#pragma unroll
    for (int n = 0; n < 4; ++n) acc[m][n] = fzero;

  auto stage = [&](int kt, int bufi) {
#pragma unroll
    for (int i = 0; i < 4; ++i) {
      int s = i*512 + tid;
      int r = s >> 3, c = (s & 7) ^ (r & 7);
      async_copy16((char*)&Alds[bufi][0] + i*8192 + w*1024,
                   &A[(am0 + r)*(long)lda + kofs + kt + c*8]);
    }
#pragma unroll
    for (int i = 0; i < 4; ++i) {
      int s = i*512 + tid;
      int r = s >> 3, c = (s & 7) ^ (r & 7);
      async_copy16((char*)&Blds[bufi][0] + i*8192 + w*1024,
                   &Bt[(bn0 + r)*(long)ldbt + kofs + kt + c*8]);
    }
  };

  const int nk = K >> 6;   // BK = 64
  stage(0, 0);
  stage(64, 1);
  asm volatile("s_waitcnt vmcnt(8)" ::: "memory");   // tile 0 landed
  __builtin_amdgcn_s_barrier();
  __builtin_amdgcn_sched_barrier(0);

  for (int t = 0; t < nk; ++t) {
    const char* Ab = (const char*)&Alds[t & 1][0];
    const char* Bb = (const char*)&Blds[t & 1][0];
    bf16x8 bfv0[4], bfv1[4], af[4];
    // ---- phase 1: B kk0 + A m0..3 kk0 ----
#pragma unroll
    for (int n = 0; n < 4; ++n) {
      int r = wc*64 + n*16 + fr;
      bfv0[n] = *(const bf16x8*)(Bb + r*128 + ((kg ^ (r & 7)) << 4));
    }
#pragma unroll
    for (int m = 0; m < 4; ++m) {
      int r = wr*128 + m*16 + fr;
      af[m] = *(const bf16x8*)(Ab + r*128 + ((kg ^ (r & 7)) << 4));
    }
    asm volatile("s_waitcnt lgkmcnt(0)" ::: "memory");
    __builtin_amdgcn_sched_barrier(0);
    __builtin_amdgcn_s_setprio(1);
#pragma unroll
    for (int m = 0; m < 4; ++m)
#pragma unroll
      for (int n = 0; n < 4; ++n)
        acc[m][n] = __builtin_amdgcn_mfma_f32_16x16x32_bf16(af[m], bfv0[n], acc[m][n], 0, 0, 0);
    __builtin_amdgcn_s_setprio(0);
    // ---- phase 2: B kk1 + A m0..3 kk1 ----
#pragma unroll
    for (int n = 0; n < 4; ++n) {
      int r = wc*64 + n*16 + fr;
      bfv1[n] = *(const bf16x8*)(Bb + r*128 + (((4 + kg) ^ (r & 7)) << 4));
    }
#pragma unroll
    for (int m = 0; m < 4; ++m) {
      int r = wr*128 + m*16 + fr;
      af[m] = *(const bf16x8*)(Ab + r*128 + (((4 + kg) ^ (r & 7)) << 4));
    }
    asm volatile("s_waitcnt lgkmcnt(0)" ::: "memory");
    __builtin_amdgcn_sched_barrier(0);
    __builtin_amdgcn_s_setprio(1);
#pragma unroll
    for (int m = 0; m < 4; ++m)
#pragma unroll
      for (int n = 0; n < 4; ++n)
        acc[m][n] = __builtin_amdgcn_mfma_f32_16x16x32_bf16(af[m], bfv1[n], acc[m][n], 0, 0, 0);
    __builtin_amdgcn_s_setprio(0);
    // ---- phase 3: A m4..7 kk0 (bfv0 kept) ----
#pragma unroll
    for (int m = 0; m < 4; ++m) {
      int r = wr*128 + (m+4)*16 + fr;
      af[m] = *(const bf16x8*)(Ab + r*128 + ((kg ^ (r & 7)) << 4));
    }
    asm volatile("s_waitcnt lgkmcnt(0)" ::: "memory");
    __builtin_amdgcn_sched_barrier(0);
    __builtin_amdgcn_s_setprio(1);
#pragma unroll
    for (int m = 0; m < 4; ++m)
#pragma unroll
      for (int n = 0; n < 4; ++n)
        acc[m+4][n] = __builtin_amdgcn_mfma_f32_16x16x32_bf16(af[m], bfv0[n], acc[m+4][n], 0, 0, 0);
    __builtin_amdgcn_s_setprio(0);
    // ---- phase 4: A m4..7 kk1 (bfv1 kept) ----
#pragma unroll
    for (int m = 0; m < 4; ++m) {
      int r = wr*128 + (m+4)*16 + fr;
      af[m] = *(const bf16x8*)(Ab + r*128 + (((4 + kg) ^ (r & 7)) << 4));
    }
    asm volatile("s_waitcnt lgkmcnt(0)" ::: "memory");
    __builtin_amdgcn_sched_barrier(0);
    __builtin_amdgcn_s_setprio(1);
#pragma unroll
    for (int m = 0; m < 4; ++m)
#pragma unroll
      for (int n = 0; n < 4; ++n)
        acc[m+4][n] = __builtin_amdgcn_mfma_f32_16x16x32_bf16(af[m], bfv1[n], acc[m+4][n], 0, 0, 0);
    __builtin_amdgcn_s_setprio(0);

    if (t + 1 == nk) break;
    __builtin_amdgcn_s_barrier();            // all waves done reading buf t&1
    __builtin_amdgcn_sched_barrier(0);
    if (t + 2 < nk) {
      stage((t + 2) * 64, t & 1);            // refill the just-freed buffer
      asm volatile("s_waitcnt vmcnt(8)" ::: "memory");  // t+1 landed; t+2 in flight
    } else {
      asm volatile("s_waitcnt vmcnt(0)" ::: "memory");  // tail: drain t+1
    }
    __builtin_amdgcn_s_barrier();
    __builtin_amdgcn_sched_barrier(0);
  }

  const int rbase = kg * 4;
  const int region = (int)(bn0 >> 10);   // EPI=3: 0=q, 1=k, 2=v (block-uniform)
#pragma unroll
  for (int m = 0; m < 8; ++m) {
#pragma unroll
    for (int n = 0; n < 4; ++n) {
      long col = bn0 + wc*64 + n*16 + fr;
      float bia = (EPI == 2) ? 0.0f : bias[col];
#pragma unroll
      for (int j = 0; j < 4; ++j) {
        long row = am0 + wr*128 + m*16 + rbase + j;
        float val = acc[m][n][j] + bia;
        if (EPI == 1) {
          ((bf16*)Cout)[row * N + col] = (bf16)gelu_f(val);
        } else if (EPI == 2) {
          ((bf16*)Cout)[((long)kz * NM + row) * N + col] = (bf16)val;
        } else {
          long cv = col & 1023;
          if (region <= 1) {
            float pval = __shfl_xor(val, 1);     // partner dim (col^1), same row
            if (n < 2) {                         // d = n*16+fr < 32: rotate
              float2 cs = rtab[((row & (NS-1)) << 4) | ((n*16 + fr) >> 1)];
              val = (fr & 1) ? val*cs.x + pval*cs.y : val*cs.x - pval*cs.y;
            }
            if (region == 0) val *= QKSCALE;
          } else {
            val *= m01f[row];                    // premask V (masked keys -> 0)
          }
          ((bf16*)Cout)[(long)region * (NM*(long)ND) + row * ND + cv] = (bf16)val;
        }
      }
    }
  }
}

// ---------------- 128^2 GEMM, 8 waves, BK=64, depth-2 counted vmcnt --------
__global__ __launch_bounds__(512, 1) void gemm128x8_kernel(
    const bf16* __restrict__ A, const bf16* __restrict__ Bt,
    const float* __restrict__ bias, const float* __restrict__ res,
    float* __restrict__ Cout, int M, int N, int K) {
  __shared__ __align__(16) bf16 Alds[4][128*64];   // 16KB per buffer
  __shared__ __align__(16) bf16 Blds[4][128*64];
  const int tid = threadIdx.x, lane = tid & 63, w = tid >> 6;
  const int fr = lane & 15, kg = lane >> 4;
  const int wr = w >> 1, wc = w & 1;   // 4M x 2N

  const int gx = gridDim.x;
  int lin = blockIdx.y * gx + blockIdx.x;
  int nwg = gx * gridDim.y;
  int swz = (lin & 7) * (nwg >> 3) + (lin >> 3);
  const long am0 = (long)(swz / gx) * 128;
  const long bn0 = (long)(swz % gx) * 128;

  const f32x4 fzero = {0.f, 0.f, 0.f, 0.f};
  f32x4 acc[2][4];
#pragma unroll
  for (int m = 0; m < 2; ++m)
#pragma unroll
    for (int n = 0; n < 4; ++n) acc[m][n] = fzero;

  auto stage = [&](int kt, int bufi) {
#pragma unroll
    for (int i = 0; i < 2; ++i) {
      int s = i*512 + tid;
      int r = s >> 3, c = (s & 7) ^ (r & 7);
      async_copy16((char*)&Alds[bufi][0] + i*8192 + w*1024,
                   &A[(am0 + r)*K + kt + c*8]);
      async_copy16((char*)&Blds[bufi][0] + i*8192 + w*1024,
                   &Bt[(bn0 + r)*K + kt + c*8]);
    }
  };

  const int nk = K >> 6;
  stage(0, 0);
  stage(64, 1);
  asm volatile("s_waitcnt vmcnt(4)" ::: "memory");
  __builtin_amdgcn_s_barrier();
  __builtin_amdgcn_sched_barrier(0);

  for (int t = 0; t < nk; ++t) {
    const int cur = t & 3;
    if (t + 2 < nk) stage((t + 2) * 64, (t + 2) & 3);
    const char* Ab = (const char*)&Alds[cur][0];
    const char* Bb = (const char*)&Blds[cur][0];
    bf16x8 af[2][2], bfv[2][4];
#pragma unroll
    for (int kk = 0; kk < 2; ++kk) {
#pragma unroll
      for (int m = 0; m < 2; ++m) {
        int r = wr*32 + m*16 + fr;
        af[kk][m] = *(const bf16x8*)(Ab + r*128 + (((kk*4 + kg) ^ (r & 7)) << 4));
      }
#pragma unroll
      for (int n = 0; n < 4; ++n) {
        int r = wc*64 + n*16 + fr;
        bfv[kk][n] = *(const bf16x8*)(Bb + r*128 + (((kk*4 + kg) ^ (r & 7)) << 4));
      }
    }
    asm volatile("s_waitcnt lgkmcnt(0)" ::: "memory");
    __builtin_amdgcn_sched_barrier(0);
    __builtin_amdgcn_s_setprio(1);
#pragma unroll
    for (int kk = 0; kk < 2; ++kk)
#pragma unroll
      for (int m = 0; m < 2; ++m)
#pragma unroll
        for (int n = 0; n < 4; ++n)
          acc[m][n] = __builtin_amdgcn_mfma_f32_16x16x32_bf16(af[kk][m], bfv[kk][n], acc[m][n], 0, 0, 0);
    __builtin_amdgcn_s_setprio(0);
    if (t + 2 < nk) { asm volatile("s_waitcnt vmcnt(4)" ::: "memory"); }
    else            { asm volatile("s_waitcnt vmcnt(0)" ::: "memory"); }
    __builtin_amdgcn_s_barrier();
    __builtin_amdgcn_sched_barrier(0);
  }

  const int rbase = kg * 4;
#pragma unroll
  for (int m = 0; m < 2; ++m) {
#pragma unroll
    for (int n = 0; n < 4; ++n) {
      long col = bn0 + wc*64 + n*16 + fr;
      float bia = bias[col];
#pragma unroll
      for (int j = 0; j < 4; ++j) {
        long row = am0 + wr*32 + m*16 + rbase + j;
        Cout[row * N + col] = acc[m][n][j] + bia + res[row * N + col];
      }
    }
  }
}

// ---------------- flash attention v9: v7 + fzero-as-C (no sacc clear) ------
// 8 waves / 128 q-rows; KVlds[4][2][64*64]; pinned offsets; imm-folded reads;
// 4-tile unrolled loop; counted vmcnt(2); mask row in LDS; l-sum via MFMA.
__global__ __launch_bounds__(512, 4) void attn_kernel(
    const bf16* __restrict__ q, const bf16* __restrict__ k,
    const bf16* __restrict__ vt, const bf16* __restrict__ m01b,
    bf16* __restrict__ out) {
  int lin = blockIdx.y * 16 + blockIdx.x;       // grid (16, 32) = 512 blocks
  int swz = (lin & 7) * 64 + (lin >> 3);
  const int qt = swz & 15;                      // 16 q-tiles of 128 rows
  const int bh = swz >> 4;                      // 0..31
  const int b = bh >> 4, h = bh & 15;
  const int tid = threadIdx.x, lane = tid & 63, w = tid >> 6;
  const int fr = lane & 15, kg = lane >> 4;
  const int k8 = kg * 8;
  const int frl = fr & 3, frh = fr >> 2;

  // K of buf i at byte (i*16384), V of buf i at (i*16384 + 8192). 64KB total.
  __shared__ __align__(16) bf16 KVlds[4][2][64*64];
  __shared__ __align__(16) bf16 Mlds[NS];         // mask01 row (4KB)

  const long qrow = (long)qt*128 + w*16 + fr;
  const bf16* qbase = q + ((long)b*NS + qrow)*ND + h*NHD;
  bf16x8 qf[2];
  qf[0] = *(const bf16x8*)(qbase + k8);
  qf[1] = *(const bf16x8*)(qbase + 32 + k8);

  const bf16* kbase = k + (long)b*NS*ND + h*NHD;
  const bf16* vtb = vt + (long)bh*64*NS;
  const bf16* mbase = m01b + (long)b*NS;

  if (w < 4) async_copy16((char*)Mlds + w*1024, mbase + tid*8);

  // ---- pinned per-lane LDS byte offsets (opaque to remat) ----
  int aK[4][2], aV[2][4];
#pragma unroll
  for (int n = 0; n < 4; ++n) {
    int r = (frh << 3) + ((n & 1) << 2) + frl + ((n >> 1) << 5);
    int swzr = (r & 7) ^ (((r >> 3) & 1) << 2);
#pragma unroll
    for (int kk = 0; kk < 2; ++kk) {
      aK[n][kk] = r*128 + ((((kk << 2) | kg) ^ swzr) << 4);
      asm("" : "+v"(aK[n][kk]));
    }
  }
#pragma unroll
  for (int kk = 0; kk < 2; ++kk)
#pragma unroll
    for (int n2 = 0; n2 < 4; ++n2) {
      int r = n2*16 + fr;
      aV[kk][n2] = r*128 + ((((kk << 2) | kg) ^ (r & 7)) << 4);
      asm("" : "+v"(aV[kk][n2]));
    }

  // ---- staging pointers (advance per tile) ----
  const int srow = tid >> 3, sc = tid & 7;
  const int csK = (sc ^ (srow & 7) ^ (((srow >> 3) & 1) << 2));
  const int csV = (sc ^ (srow & 7));
  const bf16* kp = kbase + (long)srow*ND + csK*8;
  const bf16* vp = vtb + (long)srow*NS + csV*8;
  const int ldsoff = w*1024;

  const f32x4 fzero = {0.f, 0.f, 0.f, 0.f};
  f32x4 oacc[4], oaccL = fzero;
#pragma unroll
  for (int n = 0; n < 4; ++n) oacc[n] = fzero;

  // prologue: stage tiles 0 (buf0) and 1 (buf1)
  async_copy16((char*)KVlds + 0*16384 + ldsoff, kp);
  async_copy16((char*)KVlds + 0*16384 + 8192 + ldsoff, vp);
  kp += 64*ND; vp += 64;
  async_copy16((char*)KVlds + 1*16384 + ldsoff, kp);
  async_copy16((char*)KVlds + 1*16384 + 8192 + ldsoff, vp);
  kp += 64*ND; vp += 64;
  asm volatile("s_waitcnt vmcnt(2)" ::: "memory");
  __builtin_amdgcn_s_barrier();
  __builtin_amdgcn_sched_barrier(0);

  const int NT = NS / 64;   // 32

#define ATTN_TILE(KT, BUF)                                                     \
  {                                                                            \
    const int kt_ = (KT);                                                      \
    if (kt_ + 2 < NT) {                                                        \
      async_copy16((char*)KVlds + (((BUF)+2)&3)*16384 + ldsoff, kp);           \
      async_copy16((char*)KVlds + (((BUF)+2)&3)*16384 + 8192 + ldsoff, vp);    \
      kp += 64*ND; vp += 64;                                                   \
    }                                                                          \
    bf16x8 vbm0 = *(const bf16x8*)&Mlds[kt_*64 + k8];                          \
    bf16x8 vbm1 = *(const bf16x8*)&Mlds[kt_*64 + 32 + k8];                     \
    f32x4 sacc[4];                                                             \
    _Pragma("unroll")                                                          \
    for (int n = 0; n < 4; ++n) {                                              \
      bf16x8 kf0 = *(const bf16x8*)((const char*)KVlds + (BUF)*16384 +         \
                                    aK[n][0]);                                 \
      sacc[n] = __builtin_amdgcn_mfma_f32_16x16x32_bf16(kf0, qf[0], fzero,     \
                                                        0, 0, 0);              \
      bf16x8 kf1 = *(const bf16x8*)((const char*)KVlds + (BUF)*16384 +         \
                                    aK[n][1]);                                 \
      sacc[n] = __builtin_amdgcn_mfma_f32_16x16x32_bf16(kf1, qf[1], sacc[n],   \
                                                        0, 0, 0);              \
    }                                                                          \
    float p[4][4];                                                             \
    _Pragma("unroll")                                                          \
    for (int n = 0; n < 4; ++n) {                                              \
      p[n][0] = exp2f(sacc[n][0]);                                             \
      p[n][1] = exp2f(sacc[n][1]);                                             \
      p[n][2] = exp2f(sacc[n][2]);                                             \
      p[n][3] = exp2f(sacc[n][3]);                                             \
    }                                                                          \
    bf16x8 paf[2];                                                             \
    _Pragma("unroll")                                                          \
    for (int n = 0; n < 4; ++n) {                                              \
      _Pragma("unroll")                                                        \
      for (int j = 0; j < 4; ++j)                                              \
        paf[n >> 1][((n & 1) << 2) + j] = (bf16)p[n][j];                       \
    }                                                                          \
    oaccL = __builtin_amdgcn_mfma_f32_16x16x32_bf16(paf[0], vbm0, oaccL,       \
                                                    0, 0, 0);                  \
    oaccL = __builtin_amdgcn_mfma_f32_16x16x32_bf16(paf[1], vbm1, oaccL,       \
                                                    0, 0, 0);                  \
    _Pragma("unroll")                                                          \
    for (int kk = 0; kk < 2; ++kk) {                                           \
      _Pragma("unroll")                                                        \
      for (int n2 = 0; n2 < 4; ++n2) {                                         \
        bf16x8 vb8 = *(const bf16x8*)((const char*)KVlds + (BUF)*16384 +       \
                                      8192 + aV[kk][n2]);                      \
        oacc[n2] = __builtin_amdgcn_mfma_f32_16x16x32_bf16(paf[kk], vb8,       \
                                                           oacc[n2], 0, 0, 0); \
      }                                                                        \
    }                                                                          \
    if (kt_ + 2 < NT)      { asm volatile("s_waitcnt vmcnt(2)" ::: "memory"); }\
    else if (kt_ + 1 < NT) { asm volatile("s_waitcnt vmcnt(0)" ::: "memory"); }\
    __builtin_amdgcn_s_barrier();                                              \
    __builtin_amdgcn_sched_barrier(0);                                         \
  }

  for (int it = 0; it < NT/4; ++it) {
    int kt0 = it * 4;
    ATTN_TILE(kt0 + 0, 0)
    ATTN_TILE(kt0 + 1, 1)
    ATTN_TILE(kt0 + 2, 2)
    ATTN_TILE(kt0 + 3, 3)
  }
#undef ATTN_TILE

  // epilogue: O / l  (oaccL[j] is the row-sum for row kg*4+j, all lanes agree)
#pragma unroll
  for (int j = 0; j < 4; ++j) {
    float inv = 1.0f / oaccL[j];
    long orow = (long)qt*128 + w*16 + kg*4 + j;
    bf16* ob = out + ((long)b*NS + orow)*ND + h*NHD;
#pragma unroll
    for (int n2 = 0; n2 < 4; ++n2) ob[n2*16 + fr] = (bf16)(oacc[n2][j] * inv);
  }
}

// ---------------------------------------------------------------------------
extern "C" void kernel_launch(void* const* d_in, const int* in_sizes, int n_in,
                              void* d_out, int out_size, void* d_ws, size_t ws_size,
                              hipStream_t stream) {
  const float* x    = (const float*)d_in[0];
  const int*   mask = (const int*)d_in[1];
  const float* wq   = (const float*)d_in[2];
  const float* bq   = (const float*)d_in[3];
  const float* wk   = (const float*)d_in[4];
  const float* bk   = (const float*)d_in[5];
  const float* wv   = (const float*)d_in[6];
  const float* bv   = (const float*)d_in[7];
  const float* wo   = (const float*)d_in[8];
  const float* bo   = (const float*)d_in[9];
  const float* ln1w = (const float*)d_in[10];
  const float* ln1b = (const float*)d_in[11];
  const float* ln2w = (const float*)d_in[12];
  const float* ln2b = (const float*)d_in[13];
  const float* w1   = (const float*)d_in[14];
  const float* b1   = (const float*)d_in[15];
  const float* w2   = (const float*)d_in[16];
  const float* b2   = (const float*)d_in[17];
  float* out = (float*)d_out;

  char* ws = (char*)d_ws;
  const size_t MB = 1024ull * 1024ull;
  bf16* wqt = (bf16*)(ws + 0*MB);    // wq|wk|wv contiguous for fused QKV
  bf16* wkt = (bf16*)(ws + 2*MB);
  bf16* wvt = (bf16*)(ws + 4*MB);
  bf16* wot = (bf16*)(ws + 6*MB);
  bf16* w1t = (bf16*)(ws + 8*MB);    // 8MB
  bf16* w2t = (bf16*)(ws + 16*MB);   // 8MB
  bf16* h1   = (bf16*)(ws + 24*MB);  // ln1 out (dead after QKV)
  bf16* qb   = (bf16*)(ws + 32*MB);  // q | k | v contiguous (8MB each)
  bf16* kb   = (bf16*)(ws + 40*MB);
  bf16* vb   = (bf16*)(ws + 48*MB);  // v row-major (dead after vtrans)
  bf16* vtb  = h1;                   // vt[b][h][d][s] reuses h1 slot
  bf16* attnb = (bf16*)(ws + 72*MB); // attn out (consumed before ln2 -> h2)
  bf16* f1   = (bf16*)(ws + 24*MB);  // FFN1 out 32MB, alias vt/q/k/v (dead)
  float* y1  = (float*)(ws + 56*MB); // 16MB
  bf16* h2   = (bf16*)(ws + 72*MB);  // 8MB (after attnb consumed)
  float* bcat = (float*)(ws + 80*MB);            // 12KB
  float* m01f = (float*)(ws + 80*MB + 16*1024);  // 16KB (B*S f32)
  bf16*  m01b = (bf16*) (ws + 80*MB + 32*1024);  // 8KB  (B*S bf16)
  float2* rtab = (float2*)(ws + 80*MB + 48*1024);// 256KB (S*16 float2)
  bf16* pK   = (bf16*)(ws + 84*MB);              // 32MB: 4 x [NM][ND] bf16
  const bool use_splitk = (ws_size >= 116ull*MB);
  (void)in_sizes; (void)n_in; (void)out_size;

  // prep: all weight transposes + bias concat + mask01 + rope table + ln1
  prep_kernel<<<10396, 256, 0, stream>>>(wq, wk, wv, wo, w1, w2,
                                         wqt, wkt, wvt, wot, w1t, w2t,
                                         bq, bk, bv, bcat, mask, m01f, m01b,
                                         rtab, x, ln1w, ln1b, h1);

  // fused QKV (256^2 core) + RoPE(q,k) + scale(q) + premask(v, row-major)
  gemm256_kernel<3><<<dim3(12, 16), 512, 0, stream>>>(h1, wqt, bcat, qb,
                                                      rtab, m01f, NM, 3*ND, ND,
                                                      ND, ND);
  // v[b,s,h,d] -> vt[b,h,d,s]  (h1 slot; h1 is dead now)
  vtrans_kernel<<<dim3(32, 32), 256, 0, stream>>>(vb, vtb);

  attn_kernel<<<dim3(16, 32), 512, 0, stream>>>(qb, kb, vtb, m01b, attnb);

  // out-proj + residual(x) -> y1 (fp32)
  gemm128x8_kernel<<<dim3(8, 32), 512, 0, stream>>>(attnb, wot, bo, x, y1,
                                                    NM, ND, ND);
  ln_kernel<<<NM, 256, 0, stream>>>(y1, ln2w, ln2b, h2);
  // FFN1 + GELU (256^2 core) -> f1 (bf16)
  gemm256_kernel<1><<<dim3(16, 16), 512, 0, stream>>>(h2, w1t, b1, f1,
                                                      nullptr, nullptr,
                                                      NM, NFF, ND, ND, ND);
  if (use_splitk) {
    // FFN2 split-K4 (256^2 core per slice) -> bf16 partials + fused reduce
    gemm256_kernel<2><<<dim3(4, 16, 4), 512, 0, stream>>>(f1, w2t, nullptr, pK,
                                                          nullptr, nullptr,
                                                          NM, ND, ND, NFF, NFF);
    ffn2red_kernel<<<2048, 256, 0, stream>>>(pK, y1, b2, out);
  } else {
    // fallback: R8 path
    gemm128x8_kernel<<<dim3(8, 32), 512, 0, stream>>>(f1, w2t, b2, y1, out,
                                                      NM, ND, NFF);
  }
}

// Round 16
// 262.192 us; speedup vs baseline: 1.0062x; 1.0015x over previous
//
#include <hip/hip_runtime.h>
#include <cstdint>
#include <cstddef>

// ---------------------------------------------------------------------------
// TransformerEncoderLayer  B=2 S=2048 D=1024 H=16 HD=64 FF=4096
// bf16 MFMA compute, fp32 accum/softmax/LN.
// R16: GEMM staging addresses hoisted to precomputed per-lane base pointers
//      (uniform +kt / +i*64*ld offsets) in gemm256 and gemm128x8 -- removes
//      per-K-tile address recompute from the serial inter-barrier path.
//      Everything else frozen from R15.
// ---------------------------------------------------------------------------

typedef __bf16 bf16;
typedef __bf16 bf16x2 __attribute__((ext_vector_type(2)));
typedef __bf16 bf16x4v __attribute__((ext_vector_type(4)));
typedef __bf16 bf16x8 __attribute__((ext_vector_type(8)));
typedef float  f32x4  __attribute__((ext_vector_type(4)));

#define NB 2
#define NS 2048
#define ND 1024
#define NH 16
#define NHD 64
#define NFF 4096
#define NM (NB*NS)   // 4096 rows
#define QKSCALE 0.18033688011112042f   // 0.125 * log2(e)

typedef uint32_t __attribute__((address_space(1))) gu32_t;
typedef uint32_t __attribute__((address_space(3))) lu32_t;
__device__ __forceinline__ void async_copy16(void* lds, const void* g) {
  __builtin_amdgcn_global_load_lds((gu32_t*)g, (lu32_t*)lds, 16, 0, 0);
}

__device__ __forceinline__ float gelu_f(float x) {
  return 0.5f * x * (1.0f + erff(x * 0.70710678118654752f));
}

// ---------------- prep: weight transposes + bias concat + mask + rtab + ln1 -
__global__ __launch_bounds__(256) void prep_kernel(
    const float* __restrict__ wq, const float* __restrict__ wk,
    const float* __restrict__ wv, const float* __restrict__ wo,
    const float* __restrict__ w1, const float* __restrict__ w2,
    bf16* __restrict__ wqt, bf16* __restrict__ wkt, bf16* __restrict__ wvt,
    bf16* __restrict__ wot, bf16* __restrict__ w1t, bf16* __restrict__ w2t,
    const float* __restrict__ bq, const float* __restrict__ bk,
    const float* __restrict__ bv, float* __restrict__ bcat,
    const int* __restrict__ mask, float* __restrict__ m01f,
    bf16* __restrict__ m01b, float2* __restrict__ rtab,
    const float* __restrict__ x, const float* __restrict__ ln1w,
    const float* __restrict__ ln1b, bf16* __restrict__ h1) {
  int flat = blockIdx.x;
  int t = threadIdx.x;
  if (flat < 6144) {  // ---- weight transpose + cvt (64x32 in-tile) ----
    __shared__ float tile[64][33];
    const float* W; bf16* Wt; long bx, by; int K, N;
    if (flat < 2048) {
      int which = flat >> 9, r = flat & 511;
      const float* Ws[4] = {wq, wk, wv, wo};
      bf16* Wts[4] = {wqt, wkt, wvt, wot};
      W = Ws[which]; Wt = Wts[which]; bx = r & 31; by = r >> 5; K = ND; N = ND;
    } else if (flat < 4096) {
      int r = flat - 2048;
      W = w1; Wt = w1t; bx = r & 127; by = r >> 7; K = ND; N = NFF;
    } else {
      int r = flat - 4096;
      W = w2; Wt = w2t; bx = r & 31; by = r >> 5; K = NFF; N = ND;
    }
    int tx = t & 31, ty = t >> 5;
#pragma unroll
    for (int rr = 0; rr < 8; ++rr)
      tile[rr*8 + ty][tx] = W[(by*64 + rr*8 + ty) * (long)N + bx*32 + tx];
    __syncthreads();
#pragma unroll
    for (int rr = 0; rr < 4; ++rr) {
      int ory = ty*4 + rr;              // output row within tile (input col)
      bf16x2 v2;
      v2[0] = (bf16)tile[2*tx][ory];
      v2[1] = (bf16)tile[2*tx + 1][ory];
      *(bf16x2*)&Wt[(bx*32 + ory) * (long)K + by*64 + 2*tx] = v2;
    }
  } else if (flat < 6300) {  // ---- small buffers ----
    int blk = flat - 6144;
    if (blk < 12) {
      int i = blk * 256 + t;  // 3072
      bcat[i] = (i < ND) ? bq[i] : ((i < 2*ND) ? bk[i - ND] : bv[i - 2*ND]);
    } else if (blk < 28) {
      int i = (blk - 12) * 256 + t;  // 4096 = B*S
      float v = mask[i] ? 1.0f : 0.0f;
      m01f[i] = v;
      m01b[i] = (bf16)v;
    } else {
      int idx = (blk - 28) * 256 + t;  // 32768 = S*16
      int s = idx >> 4, i = idx & 15;
      float ang = (float)s * exp2f(-(float)i * (13.287712379549449f / 16.0f));
      float sn, cs;
      sincosf(ang, &sn, &cs);
      rtab[idx] = make_float2(cs, sn);
    }
  } else {  // ---- ln1 ----
    long row = flat - 6300;
    float4 v = ((const float4*)(x + row*ND))[t];
    float s  = v.x + v.y + v.z + v.w;
    float sq = v.x*v.x + v.y*v.y + v.z*v.z + v.w*v.w;
#pragma unroll
    for (int m = 1; m <= 32; m <<= 1) { s += __shfl_xor(s, m); sq += __shfl_xor(sq, m); }
    __shared__ float ss[4], ssq[4];
    if ((t & 63) == 0) { ss[t>>6] = s; ssq[t>>6] = sq; }
    __syncthreads();
    s  = ss[0] + ss[1] + ss[2] + ss[3];
    sq = ssq[0] + ssq[1] + ssq[2] + ssq[3];
    float mu = s * (1.0f/ND);
    float rs = rsqrtf(sq * (1.0f/ND) - mu*mu + 1e-5f);
    float4 wv4 = ((const float4*)ln1w)[t];
    float4 bv4 = ((const float4*)ln1b)[t];
    bf16x4v o;
    o[0] = (bf16)((v.x-mu)*rs*wv4.x + bv4.x);
    o[1] = (bf16)((v.y-mu)*rs*wv4.y + bv4.y);
    o[2] = (bf16)((v.z-mu)*rs*wv4.z + bv4.z);
    o[3] = (bf16)((v.w-mu)*rs*wv4.w + bv4.w);
    *(bf16x4v*)(h1 + row*ND + t*4) = o;
  }
}

// ---------------- V transpose: v[b,s,h,d] -> vt[b,h,d,s] -------------------
__global__ __launch_bounds__(256) void vtrans_kernel(
    const bf16* __restrict__ v, bf16* __restrict__ vt) {
  __shared__ bf16 t[64][66];
  int st = blockIdx.x, bh = blockIdx.y;   // 32 x 32
  int b = bh >> 4, h = bh & 15;
  int c = threadIdx.x & 63, rg = threadIdx.x >> 6;
  const bf16* src = v + ((long)b*NS + st*64)*ND + h*64;
#pragma unroll
  for (int i = 0; i < 16; ++i) {
    int r = rg*16 + i;
    t[r][c] = src[(long)r*ND + c];
  }
  __syncthreads();
  bf16* dst = vt + (long)bh*64*NS + st*64;
#pragma unroll
  for (int i = 0; i < 16; ++i) {
    int d = rg*16 + i;
    dst[(long)d*NS + c] = t[c][d];
  }
}

// ---------------- layernorm fp32 -> bf16 (ln2) ------------------------------
__global__ __launch_bounds__(256) void ln_kernel(
    const float* __restrict__ x, const float* __restrict__ w,
    const float* __restrict__ b, bf16* __restrict__ out) {
  long row = blockIdx.x;
  int t = threadIdx.x;
  float4 v = ((const float4*)(x + row*ND))[t];
  float s  = v.x + v.y + v.z + v.w;
  float sq = v.x*v.x + v.y*v.y + v.z*v.z + v.w*v.w;
#pragma unroll
  for (int m = 1; m <= 32; m <<= 1) { s += __shfl_xor(s, m); sq += __shfl_xor(sq, m); }
  __shared__ float ss[4], ssq[4];
  if ((t & 63) == 0) { ss[t>>6] = s; ssq[t>>6] = sq; }
  __syncthreads();
  s  = ss[0] + ss[1] + ss[2] + ss[3];
  sq = ssq[0] + ssq[1] + ssq[2] + ssq[3];
  float mu = s * (1.0f/ND);
  float rs = rsqrtf(sq * (1.0f/ND) - mu*mu + 1e-5f);
  float4 wv = ((const float4*)w)[t];
  float4 bv = ((const float4*)b)[t];
  bf16x4v o;
  o[0] = (bf16)((v.x-mu)*rs*wv.x + bv.x);
  o[1] = (bf16)((v.y-mu)*rs*wv.y + bv.y);
  o[2] = (bf16)((v.z-mu)*rs*wv.z + bv.z);
  o[3] = (bf16)((v.w-mu)*rs*wv.w + bv.w);
  *(bf16x4v*)(out + row*ND + t*4) = o;
}

// ---------------- FFN2 split-K reduce (bf16 partials): out = sum + y1 + b2 -
__global__ __launch_bounds__(256) void ffn2red_kernel(
    const bf16* __restrict__ P, const float* __restrict__ y1,
    const float* __restrict__ b2, float* __restrict__ out) {
  const long n8 = (long)NM * ND / 8;   // groups of 8 elems
  for (long i = (long)blockIdx.x*256 + threadIdx.x; i < n8;
       i += (long)gridDim.x*256) {
    bf16x8 p0 = ((const bf16x8*)P)[i];
    bf16x8 p1 = ((const bf16x8*)P)[i + n8];
    bf16x8 p2 = ((const bf16x8*)P)[i + 2*n8];
    bf16x8 p3 = ((const bf16x8*)P)[i + 3*n8];
    float4 ya = ((const float4*)y1)[2*i];
    float4 yb = ((const float4*)y1)[2*i + 1];
    int cb = (int)((i * 8) & 1023);
    float4 ba = *(const float4*)&b2[cb];
    float4 bb = *(const float4*)&b2[cb + 4];
    float4 ra, rb;
    ra.x = ((float)p0[0]+(float)p1[0])+((float)p2[0]+(float)p3[0]) + ya.x + ba.x;
    ra.y = ((float)p0[1]+(float)p1[1])+((float)p2[1]+(float)p3[1]) + ya.y + ba.y;
    ra.z = ((float)p0[2]+(float)p1[2])+((float)p2[2]+(float)p3[2]) + ya.z + ba.z;
    ra.w = ((float)p0[3]+(float)p1[3])+((float)p2[3]+(float)p3[3]) + ya.w + ba.w;
    rb.x = ((float)p0[4]+(float)p1[4])+((float)p2[4]+(float)p3[4]) + yb.x + bb.x;
    rb.y = ((float)p0[5]+(float)p1[5])+((float)p2[5]+(float)p3[5]) + yb.y + bb.y;
    rb.z = ((float)p0[6]+(float)p1[6])+((float)p2[6]+(float)p3[6]) + yb.z + bb.z;
    rb.w = ((float)p0[7]+(float)p1[7])+((float)p2[7]+(float)p3[7]) + yb.w + bb.w;
    ((float4*)out)[2*i]     = ra;
    ((float4*)out)[2*i + 1] = rb;
  }
}

// ---------------- 256^2 GEMM core (R10): BK=64, dist-2, vmcnt(8) -----------
// Staging via precomputed per-lane base pointers (R16).
template<int EPI>
__global__ __launch_bounds__(512, 2) void gemm256_kernel(
    const bf16* __restrict__ A, const bf16* __restrict__ Bt,
    const float* __restrict__ bias, void* __restrict__ Cout,
    const float2* __restrict__ rtab, const float* __restrict__ m01f,
    int M, int N, int K, int lda, int ldbt) {
  __shared__ __align__(16) bf16 Alds[2][256*64];   // 32KB per buffer
  __shared__ __align__(16) bf16 Blds[2][256*64];
  const int tid = threadIdx.x, lane = tid & 63, w = tid >> 6;
  const int fr = lane & 15, kg = lane >> 4;
  const int wr = w >> 2, wc = w & 3;   // 2M x 4N, wave tile 128x64
  const int kz = (EPI == 2) ? blockIdx.z : 0;
  const long kofs = (long)kz * K;      // EPI=2: slice offset in K

  const int gx = gridDim.x;
  int lin = blockIdx.y * gx + blockIdx.x;
  int nwg = gx * gridDim.y;
  int swz = (lin & 7) * (nwg >> 3) + (lin >> 3);
  const long am0 = (long)(swz / gx) * 256;
  const long bn0 = (long)(swz % gx) * 256;

  const f32x4 fzero = {0.f, 0.f, 0.f, 0.f};
  f32x4 acc[8][4];
#pragma unroll
  for (int m = 0; m < 8; ++m)
#pragma unroll
    for (int n = 0; n < 4; ++n) acc[m][n] = fzero;

  // staging bases: row = i*64 + srow, swizzled chunk scol (loop-invariant)
  const int srow = tid >> 3;
  const int scol = (tid & 7) ^ (srow & 7);
  const bf16* pA = A + (am0 + srow) * (long)lda + kofs + scol*8;
  const bf16* pB = Bt + (bn0 + srow) * (long)ldbt + kofs + scol*8;

  auto stage = [&](int kt, int bufi) {
#pragma unroll
    for (int i = 0; i < 4; ++i)
      async_copy16((char*)&Alds[bufi][0] + i*8192 + w*1024,
                   pA + (long)(i*64)*lda + kt);
#pragma unroll
    for (int i = 0; i < 4; ++i)
      async_copy16((char*)&Blds[bufi][0] + i*8192 + w*1024,
                   pB + (long)(i*64)*ldbt + kt);
  };

  const int nk = K >> 6;   // BK = 64
  stage(0, 0);
  stage(64, 1);
  asm volatile("s_waitcnt vmcnt(8)" ::: "memory");   // tile 0 landed
  __builtin_amdgcn_s_barrier();
  __builtin_amdgcn_sched_barrier(0);

  for (int t = 0; t < nk; ++t) {
    const char* Ab = (const char*)&Alds[t & 1][0];
    const char* Bb = (const char*)&Blds[t & 1][0];
    bf16x8 bfv0[4], bfv1[4], af[4];
    // ---- phase 1: B kk0 + A m0..3 kk0 ----
#pragma unroll
    for (int n = 0; n < 4; ++n) {
      int r = wc*64 + n*16 + fr;
      bfv0[n] = *(const bf16x8*)(Bb + r*128 + ((kg ^ (r & 7)) << 4));
    }
#pragma unroll
    for (int m = 0; m < 4; ++m) {
      int r = wr*128 + m*16 + fr;
      af[m] = *(const bf16x8*)(Ab + r*128 + ((kg ^ (r & 7)) << 4));
    }
    asm volatile("s_waitcnt lgkmcnt(0)" ::: "memory");
    __builtin_amdgcn_sched_barrier(0);
    __builtin_amdgcn_s_setprio(1);
#pragma unroll
    for (int m = 0; m < 4; ++m)
#pragma unroll
      for (int n = 0; n < 4; ++n)
        acc[m][n] = __builtin_amdgcn_mfma_f32_16x16x32_bf16(af[m], bfv0[n], acc[m][n], 0, 0, 0);
    __builtin_amdgcn_s_setprio(0);
    // ---- phase 2: B kk1 + A m0..3 kk1 ----
#pragma unroll
    for (int n = 0; n < 4; ++n) {
      int r = wc*64 + n*16 + fr;
      bfv1[n] = *(const bf16x8*)(Bb + r*128 + (((4 + kg) ^ (r & 7)) << 4));
    }
#pragma unroll
    for (int m = 0; m < 4; ++m) {
      int r = wr*128 + m*16 + fr;
      af[m] = *(const bf16x8*)(Ab + r*128 + (((4 + kg) ^ (r & 7)) << 4));
    }
    asm volatile("s_waitcnt lgkmcnt(0)" ::: "memory");
    __builtin_amdgcn_sched_barrier(0);
    __builtin_amdgcn_s_setprio(1);
#pragma unroll
    for (int m = 0; m < 4; ++m)
#pragma unroll
      for (int n = 0; n < 4; ++n)
        acc[m][n] = __builtin_amdgcn_mfma_f32_16x16x32_bf16(af[m], bfv1[n], acc[m][n], 0, 0, 0);
    __builtin_amdgcn_s_setprio(0);
    // ---- phase 3: A m4..7 kk0 (bfv0 kept) ----
#pragma unroll
    for (int m = 0; m < 4; ++m) {
      int r = wr*128 + (m+4)*16 + fr;
      af[m] = *(const bf16x8*)(Ab + r*128 + ((kg ^ (r & 7)) << 4));
    }
    asm volatile("s_waitcnt lgkmcnt(0)" ::: "memory");
    __builtin_amdgcn_sched_barrier(0);
    __builtin_amdgcn_s_setprio(1);
#pragma unroll
    for (int m = 0; m < 4; ++m)
#pragma unroll
      for (int n = 0; n < 4; ++n)
        acc[m+4][n] = __builtin_amdgcn_mfma_f32_16x16x32_bf16(af[m], bfv0[n], acc[m+4][n], 0, 0, 0);
    __builtin_amdgcn_s_setprio(0);
    // ---- phase 4: A m4..7 kk1 (bfv1 kept) ----
#pragma unroll
    for (int m = 0; m < 4; ++m) {
      int r = wr*128 + (m+4)*16 + fr;
      af[m] = *(const bf16x8*)(Ab + r*128 + (((4 + kg) ^ (r & 7)) << 4));
    }
    asm volatile("s_waitcnt lgkmcnt(0)" ::: "memory");
    __builtin_amdgcn_sched_barrier(0);
    __builtin_amdgcn_s_setprio(1);
#pragma unroll
    for (int m = 0; m < 4; ++m)
#pragma unroll
      for (int n = 0; n < 4; ++n)
        acc[m+4][n] = __builtin_amdgcn_mfma_f32_16x16x32_bf16(af[m], bfv1[n], acc[m+4][n], 0, 0, 0);
    __builtin_amdgcn_s_setprio(0);

    if (t + 1 == nk) break;
    __builtin_amdgcn_s_barrier();            // all waves done reading buf t&1
    __builtin_amdgcn_sched_barrier(0);
    if (t + 2 < nk) {
      stage((t + 2) * 64, t & 1);            // refill the just-freed buffer
      asm volatile("s_waitcnt vmcnt(8)" ::: "memory");  // t+1 landed; t+2 in flight
    } else {
      asm volatile("s_waitcnt vmcnt(0)" ::: "memory");  // tail: drain t+1
    }
    __builtin_amdgcn_s_barrier();
    __builtin_amdgcn_sched_barrier(0);
  }

  const int rbase = kg * 4;
  const int region = (int)(bn0 >> 10);   // EPI=3: 0=q, 1=k, 2=v (block-uniform)
#pragma unroll
  for (int m = 0; m < 8; ++m) {
#pragma unroll
    for (int n = 0; n < 4; ++n) {
      long col = bn0 + wc*64 + n*16 + fr;
      float bia = (EPI == 2) ? 0.0f : bias[col];
#pragma unroll
      for (int j = 0; j < 4; ++j) {
        long row = am0 + wr*128 + m*16 + rbase + j;
        float val = acc[m][n][j] + bia;
        if (EPI == 1) {
          ((bf16*)Cout)[row * N + col] = (bf16)gelu_f(val);
        } else if (EPI == 2) {
          ((bf16*)Cout)[((long)kz * NM + row) * N + col] = (bf16)val;
        } else {
          long cv = col & 1023;
          if (region <= 1) {
            float pval = __shfl_xor(val, 1);     // partner dim (col^1), same row
            if (n < 2) {                         // d = n*16+fr < 32: rotate
              float2 cs = rtab[((row & (NS-1)) << 4) | ((n*16 + fr) >> 1)];
              val = (fr & 1) ? val*cs.x + pval*cs.y : val*cs.x - pval*cs.y;
            }
            if (region == 0) val *= QKSCALE;
          } else {
            val *= m01f[row];                    // premask V (masked keys -> 0)
          }
          ((bf16*)Cout)[(long)region * (NM*(long)ND) + row * ND + cv] = (bf16)val;
        }
      }
    }
  }
}

// ---------------- 128^2 GEMM, 8 waves, BK=64, depth-2 counted vmcnt --------
// Staging via precomputed per-lane base pointers (R16).
__global__ __launch_bounds__(512, 1) void gemm128x8_kernel(
    const bf16* __restrict__ A, const bf16* __restrict__ Bt,
    const float* __restrict__ bias, const float* __restrict__ res,
    float* __restrict__ Cout, int M, int N, int K) {
  __shared__ __align__(16) bf16 Alds[4][128*64];   // 16KB per buffer
  __shared__ __align__(16) bf16 Blds[4][128*64];
  const int tid = threadIdx.x, lane = tid & 63, w = tid >> 6;
  const int fr = lane & 15, kg = lane >> 4;
  const int wr = w >> 1, wc = w & 1;   // 4M x 2N

  const int gx = gridDim.x;
  int lin = blockIdx.y * gx + blockIdx.x;
  int nwg = gx * gridDim.y;
  int swz = (lin & 7) * (nwg >> 3) + (lin >> 3);
  const long am0 = (long)(swz / gx) * 128;
  const long bn0 = (long)(swz % gx) * 128;

  const f32x4 fzero = {0.f, 0.f, 0.f, 0.f};
  f32x4 acc[2][4];
#pragma unroll
  for (int m = 0; m < 2; ++m)
#pragma unroll
    for (int n = 0; n < 4; ++n) acc[m][n] = fzero;

  const int srow = tid >> 3;
  const int scol = (tid & 7) ^ (srow & 7);
  const bf16* pA = A + (am0 + srow) * (long)K + scol*8;
  const bf16* pB = Bt + (bn0 + srow) * (long)K + scol*8;

  auto stage = [&](int kt, int bufi) {
#pragma unroll
    for (int i = 0; i < 2; ++i) {
      async_copy16((char*)&Alds[bufi][0] + i*8192 + w*1024,
                   pA + (long)(i*64)*K + kt);
      async_copy16((char*)&Blds[bufi][0] + i*8192 + w*1024,
                   pB + (long)(i*64)*K + kt);
    }
  };

  const int nk = K >> 6;
  stage(0, 0);
  stage(64, 1);
  asm volatile("s_waitcnt vmcnt(4)" ::: "memory");
  __builtin_amdgcn_s_barrier();
  __builtin_amdgcn_sched_barrier(0);

  for (int t = 0; t < nk; ++t) {
    const int cur = t & 3;
    if (t + 2 < nk) stage((t + 2) * 64, (t + 2) & 3);
    const char* Ab = (const char*)&Alds[cur][0];
    const char* Bb = (const char*)&Blds[cur][0];
    bf16x8 af[2][2], bfv[2][4];
#pragma unroll
    for (int kk = 0; kk < 2; ++kk) {
#pragma unroll
      for (int m = 0; m < 2; ++m) {
        int r = wr*32 + m*16 + fr;
        af[kk][m] = *(const bf16x8*)(Ab + r*128 + (((kk*4 + kg) ^ (r & 7)) << 4));
      }
#pragma unroll
      for (int n = 0; n < 4; ++n) {
        int r = wc*64 + n*16 + fr;
        bfv[kk][n] = *(const bf16x8*)(Bb + r*128 + (((kk*4 + kg) ^ (r & 7)) << 4));
      }
    }
    asm volatile("s_waitcnt lgkmcnt(0)" ::: "memory");
    __builtin_amdgcn_sched_barrier(0);
    __builtin_amdgcn_s_setprio(1);
#pragma unroll
    for (int kk = 0; kk < 2; ++kk)
#pragma unroll
      for (int m = 0; m < 2; ++m)
#pragma unroll
        for (int n = 0; n < 4; ++n)
          acc[m][n] = __builtin_amdgcn_mfma_f32_16x16x32_bf16(af[kk][m], bfv[kk][n], acc[m][n], 0, 0, 0);
    __builtin_amdgcn_s_setprio(0);
    if (t + 2 < nk) { asm volatile("s_waitcnt vmcnt(4)" ::: "memory"); }
    else            { asm volatile("s_waitcnt vmcnt(0)" ::: "memory"); }
    __builtin_amdgcn_s_barrier();
    __builtin_amdgcn_sched_barrier(0);
  }

  const int rbase = kg * 4;
#pragma unroll
  for (int m = 0; m < 2; ++m) {
#pragma unroll
    for (int n = 0; n < 4; ++n) {
      long col = bn0 + wc*64 + n*16 + fr;
      float bia = bias[col];
#pragma unroll
      for (int j = 0; j < 4; ++j) {
        long row = am0 + wr*32 + m*16 + rbase + j;
        Cout[row * N + col] = acc[m][n][j] + bia + res[row * N + col];
      }
    }
  }
}

// ---------------- flash attention v9 (unchanged from R15) ------------------
__global__ __launch_bounds__(512, 4) void attn_kernel(
    const bf16* __restrict__ q, const bf16* __restrict__ k,
    const bf16* __restrict__ vt, const bf16* __restrict__ m01b,
    bf16* __restrict__ out) {
  int lin = blockIdx.y * 16 + blockIdx.x;       // grid (16, 32) = 512 blocks
  int swz = (lin & 7) * 64 + (lin >> 3);
  const int qt = swz & 15;                      // 16 q-tiles of 128 rows
  const int bh = swz >> 4;                      // 0..31
  const int b = bh >> 4, h = bh & 15;
  const int tid = threadIdx.x, lane = tid & 63, w = tid >> 6;
  const int fr = lane & 15, kg = lane >> 4;
  const int k8 = kg * 8;
  const int frl = fr & 3, frh = fr >> 2;

  __shared__ __align__(16) bf16 KVlds[4][2][64*64];
  __shared__ __align__(16) bf16 Mlds[NS];         // mask01 row (4KB)

  const long qrow = (long)qt*128 + w*16 + fr;
  const bf16* qbase = q + ((long)b*NS + qrow)*ND + h*NHD;
  bf16x8 qf[2];
  qf[0] = *(const bf16x8*)(qbase + k8);
  qf[1] = *(const bf16x8*)(qbase + 32 + k8);

  const bf16* kbase = k + (long)b*NS*ND + h*NHD;
  const bf16* vtb = vt + (long)bh*64*NS;
  const bf16* mbase = m01b + (long)b*NS;

  if (w < 4) async_copy16((char*)Mlds + w*1024, mbase + tid*8);

  int aK[4][2], aV[2][4];
#pragma unroll
  for (int n = 0; n < 4; ++n) {
    int r = (frh << 3) + ((n & 1) << 2) + frl + ((n >> 1) << 5);
    int swzr = (r & 7) ^ (((r >> 3) & 1) << 2);
#pragma unroll
    for (int kk = 0; kk < 2; ++kk) {
      aK[n][kk] = r*128 + ((((kk << 2) | kg) ^ swzr) << 4);
      asm("" : "+v"(aK[n][kk]));
    }
  }
#pragma unroll
  for (int kk = 0; kk < 2; ++kk)
#pragma unroll
    for (int n2 = 0; n2 < 4; ++n2) {
      int r = n2*16 + fr;
      aV[kk][n2] = r*128 + ((((kk << 2) | kg) ^ (r & 7)) << 4);
      asm("" : "+v"(aV[kk][n2]));
    }

  const int srow = tid >> 3, sc = tid & 7;
  const int csK = (sc ^ (srow & 7) ^ (((srow >> 3) & 1) << 2));
  const int csV = (sc ^ (srow & 7));
  const bf16* kp = kbase + (long)srow*ND + csK*8;
  const bf16* vp = vtb + (long)srow*NS + csV*8;
  const int ldsoff = w*1024;

  const f32x4 fzero = {0.f, 0.f, 0.f, 0.f};
  f32x4 oacc[4], oaccL = fzero;
#pragma unroll
  for (int n = 0; n < 4; ++n) oacc[n] = fzero;

  async_copy16((char*)KVlds + 0*16384 + ldsoff, kp);
  async_copy16((char*)KVlds + 0*16384 + 8192 + ldsoff, vp);
  kp += 64*ND; vp += 64;
  async_copy16((char*)KVlds + 1*16384 + ldsoff, kp);
  async_copy16((char*)KVlds + 1*16384 + 8192 + ldsoff, vp);
  kp += 64*ND; vp += 64;
  asm volatile("s_waitcnt vmcnt(2)" ::: "memory");
  __builtin_amdgcn_s_barrier();
  __builtin_amdgcn_sched_barrier(0);

  const int NT = NS / 64;   // 32

#define ATTN_TILE(KT, BUF)                                                     \
  {                                                                            \
    const int kt_ = (KT);                                                      \
    if (kt_ + 2 < NT) {                                                        \
      async_copy16((char*)KVlds + (((BUF)+2)&3)*16384 + ldsoff, kp);           \
      async_copy16((char*)KVlds + (((BUF)+2)&3)*16384 + 8192 + ldsoff, vp);    \
      kp += 64*ND; vp += 64;                                                   \
    }                                                                          \
    bf16x8 vbm0 = *(const bf16x8*)&Mlds[kt_*64 + k8];                          \
    bf16x8 vbm1 = *(const bf16x8*)&Mlds[kt_*64 + 32 + k8];                     \
    f32x4 sacc[4];                                                             \
    _Pragma("unroll")                                                          \
    for (int n = 0; n < 4; ++n) {                                              \
      bf16x8 kf0 = *(const bf16x8*)((const char*)KVlds + (BUF)*16384 +         \
                                    aK[n][0]);                                 \
      sacc[n] = __builtin_amdgcn_mfma_f32_16x16x32_bf16(kf0, qf[0], fzero,     \
                                                        0, 0, 0);              \
      bf16x8 kf1 = *(const bf16x8*)((const char*)KVlds + (BUF)*16384 +         \
                                    aK[n][1]);                                 \
      sacc[n] = __builtin_amdgcn_mfma_f32_16x16x32_bf16(kf1, qf[1], sacc[n],   \
                                                        0, 0, 0);              \
    }                                                                          \
    float p[4][4];                                                             \
    _Pragma("unroll")                                                          \
    for (int n = 0; n < 4; ++n) {                                              \
      p[n][0] = exp2f(sacc[n][0]);                                             \
      p[n][1] = exp2f(sacc[n][1]);                                             \
      p[n][2] = exp2f(sacc[n][2]);                                             \
      p[n][3] = exp2f(sacc[n][3]);                                             \
    }                                                                          \
    bf16x8 paf[2];                                                             \
    _Pragma("unroll")                                                          \
    for (int n = 0; n < 4; ++n) {                                              \
      _Pragma("unroll")                                                        \
      for (int j = 0; j < 4; ++j)                                              \
        paf[n >> 1][((n & 1) << 2) + j] = (bf16)p[n][j];                       \
    }                                                                          \
    oaccL = __builtin_amdgcn_mfma_f32_16x16x32_bf16(paf[0], vbm0, oaccL,       \
                                                    0, 0, 0);                  \
    oaccL = __builtin_amdgcn_mfma_f32_16x16x32_bf16(paf[1], vbm1, oaccL,       \
                                                    0, 0, 0);                  \
    _Pragma("unroll")                                                          \
    for (int kk = 0; kk < 2; ++kk) {                                           \
      _Pragma("unroll")                                                        \
      for (int n2 = 0; n2 < 4; ++n2) {                                         \
        bf16x8 vb8 = *(const bf16x8*)((const char*)KVlds + (BUF)*16384 +       \
                                      8192 + aV[kk][n2]);                      \
        oacc[n2] = __builtin_amdgcn_mfma_f32_16x16x32_bf16(paf[kk], vb8,       \
                                                           oacc[n2], 0, 0, 0); \
      }                                                                        \
    }                                                                          \
    if (kt_ + 2 < NT)      { asm volatile("s_waitcnt vmcnt(2)" ::: "memory"); }\
    else if (kt_ + 1 < NT) { asm volatile("s_waitcnt vmcnt(0)" ::: "memory"); }\
    __builtin_amdgcn_s_barrier();                                              \
    __builtin_amdgcn_sched_barrier(0);                                         \
  }

  for (int it = 0; it < NT/4; ++it) {
    int kt0 = it * 4;
    ATTN_TILE(kt0 + 0, 0)
    ATTN_TILE(kt0 + 1, 1)
    ATTN_TILE(kt0 + 2, 2)
    ATTN_TILE(kt0 + 3, 3)
  }
#undef ATTN_TILE

#pragma unroll
  for (int j = 0; j < 4; ++j) {
    float inv = 1.0f / oaccL[j];
    long orow = (long)qt*128 + w*16 + kg*4 + j;
    bf16* ob = out + ((long)b*NS + orow)*ND + h*NHD;
#pragma unroll
    for (int n2 = 0; n2 < 4; ++n2) ob[n2*16 + fr] = (bf16)(oacc[n2][j] * inv);
  }
}

// ---------------------------------------------------------------------------
extern "C" void kernel_launch(void* const* d_in, const int* in_sizes, int n_in,
                              void* d_out, int out_size, void* d_ws, size_t ws_size,
                              hipStream_t stream) {
  const float* x    = (const float*)d_in[0];
  const int*   mask = (const int*)d_in[1];
  const float* wq   = (const float*)d_in[2];
  const float* bq   = (const float*)d_in[3];
  const float* wk   = (const float*)d_in[4];
  const float* bk   = (const float*)d_in[5];
  const float* wv   = (const float*)d_in[6];
  const float* bv   = (const float*)d_in[7];
  const float* wo   = (const float*)d_in[8];
  const float* bo   = (const float*)d_in[9];
  const float* ln1w = (const float*)d_in[10];
  const float* ln1b = (const float*)d_in[11];
  const float* ln2w = (const float*)d_in[12];
  const float* ln2b = (const float*)d_in[13];
  const float* w1   = (const float*)d_in[14];
  const float* b1   = (const float*)d_in[15];
  const float* w2   = (const float*)d_in[16];
  const float* b2   = (const float*)d_in[17];
  float* out = (float*)d_out;

  char* ws = (char*)d_ws;
  const size_t MB = 1024ull * 1024ull;
  bf16* wqt = (bf16*)(ws + 0*MB);    // wq|wk|wv contiguous for fused QKV
  bf16* wkt = (bf16*)(ws + 2*MB);
  bf16* wvt = (bf16*)(ws + 4*MB);
  bf16* wot = (bf16*)(ws + 6*MB);
  bf16* w1t = (bf16*)(ws + 8*MB);    // 8MB
  bf16* w2t = (bf16*)(ws + 16*MB);   // 8MB
  bf16* h1   = (bf16*)(ws + 24*MB);  // ln1 out (dead after QKV)
  bf16* qb   = (bf16*)(ws + 32*MB);  // q | k | v contiguous (8MB each)
  bf16* kb   = (bf16*)(ws + 40*MB);
  bf16* vb   = (bf16*)(ws + 48*MB);  // v row-major (dead after vtrans)
  bf16* vtb  = h1;                   // vt[b][h][d][s] reuses h1 slot
  bf16* attnb = (bf16*)(ws + 72*MB); // attn out (consumed before ln2 -> h2)
  bf16* f1   = (bf16*)(ws + 24*MB);  // FFN1 out 32MB, alias vt/q/k/v (dead)
  float* y1  = (float*)(ws + 56*MB); // 16MB
  bf16* h2   = (bf16*)(ws + 72*MB);  // 8MB (after attnb consumed)
  float* bcat = (float*)(ws + 80*MB);            // 12KB
  float* m01f = (float*)(ws + 80*MB + 16*1024);  // 16KB (B*S f32)
  bf16*  m01b = (bf16*) (ws + 80*MB + 32*1024);  // 8KB  (B*S bf16)
  float2* rtab = (float2*)(ws + 80*MB + 48*1024);// 256KB (S*16 float2)
  bf16* pK   = (bf16*)(ws + 84*MB);              // 32MB: 4 x [NM][ND] bf16
  const bool use_splitk = (ws_size >= 116ull*MB);
  (void)in_sizes; (void)n_in; (void)out_size;

  // prep: all weight transposes + bias concat + mask01 + rope table + ln1
  prep_kernel<<<10396, 256, 0, stream>>>(wq, wk, wv, wo, w1, w2,
                                         wqt, wkt, wvt, wot, w1t, w2t,
                                         bq, bk, bv, bcat, mask, m01f, m01b,
                                         rtab, x, ln1w, ln1b, h1);

  // fused QKV (256^2 core) + RoPE(q,k) + scale(q) + premask(v, row-major)
  gemm256_kernel<3><<<dim3(12, 16), 512, 0, stream>>>(h1, wqt, bcat, qb,
                                                      rtab, m01f, NM, 3*ND, ND,
                                                      ND, ND);
  // v[b,s,h,d] -> vt[b,h,d,s]  (h1 slot; h1 is dead now)
  vtrans_kernel<<<dim3(32, 32), 256, 0, stream>>>(vb, vtb);

  attn_kernel<<<dim3(16, 32), 512, 0, stream>>>(qb, kb, vtb, m01b, attnb);

  // out-proj + residual(x) -> y1 (fp32)
  gemm128x8_kernel<<<dim3(8, 32), 512, 0, stream>>>(attnb, wot, bo, x, y1,
                                                    NM, ND, ND);
  ln_kernel<<<NM, 256, 0, stream>>>(y1, ln2w, ln2b, h2);
  // FFN1 + GELU (256^2 core) -> f1 (bf16)
  gemm256_kernel<1><<<dim3(16, 16), 512, 0, stream>>>(h2, w1t, b1, f1,
                                                      nullptr, nullptr,
                                                      NM, NFF, ND, ND, ND);
  if (use_splitk) {
    // FFN2 split-K4 (256^2 core per slice) -> bf16 partials + fused reduce
    gemm256_kernel<2><<<dim3(4, 16, 4), 512, 0, stream>>>(f1, w2t, nullptr, pK,
                                                          nullptr, nullptr,
                                                          NM, ND, ND, NFF, NFF);
    ffn2red_kernel<<<2048, 256, 0, stream>>>(pK, y1, b2, out);
  } else {
    // fallback: R8 path
    gemm128x8_kernel<<<dim3(8, 32), 512, 0, stream>>>(f1, w2t, b2, y1, out,
                                                      NM, ND, NFF);
  }
}